// Round 1
// 151.025 us; speedup vs baseline: 1.0391x; 1.0391x over previous
//
#include <hip/hip_runtime.h>
#include <math.h>

#define BB 8
#define CCH 32
#define HH 128
#define WW 128
#define OUTC 32
#define NPIX (BB*HH*WW)          // 131072
#define HWP 131                   // padded-coord clamp limit
#define NCONVBLK 2048             // conv blocks (64 px each)

// workspace layout (float offsets) — ~18.97 MB
#define WS_XT    0                                   // fp32 x_t [b][i][j][c], 16 MB
#define WS_CONV4 (BB*HH*WW*CCH)                      // pre-BN conv, 4 f/px, 2 MB
#define WS_PART  (WS_CONV4 + BB*HH*WW*4)             // 2048*8 f per-block stats partials
#define WS_BNAB  (WS_PART + NCONVBLK*8)              // 8 f
#define WS_WKB   (WS_BNAB + 8)                       // 16384 ushort bf16 W[o][k], k=n*32+c

// k_main LDS tile: rows i0-4..i0+7 (12), cols j0-4..j0+35 (40), 5-group padding
// offset(r,cc,q) = ((r*40+cc)*5 + q)*8 ushorts = r*1600 + cc*40 + q*8
#define TILE_USH (12*40*5*8)                         // 19200 ushorts = 38400 B

typedef __attribute__((ext_vector_type(8))) short short8;
typedef __attribute__((ext_vector_type(4))) float f32x4;

__device__ __forceinline__ unsigned short f2bf(float f) {
    unsigned u = __float_as_uint(f);
    unsigned r = (u + 0x7FFFu + ((u >> 16) & 1u)) >> 16;   // RTNE
    return (unsigned short)r;
}
// hw packed RTNE f32->bf16x2 (same rounding as f2bf); no builtin on gfx950
__device__ __forceinline__ unsigned cvtpk(float lo, float hi) {
    unsigned r;
    asm("v_cvt_pk_bf16_f32 %0, %1, %2" : "=v"(r) : "v"(lo), "v"(hi));
    return r;
}
__device__ __forceinline__ float bflo(unsigned w) { return __uint_as_float(w << 16); }
__device__ __forceinline__ float bfhi(unsigned w) { return __uint_as_float(w & 0xFFFF0000u); }

// ---------------- K1: fused transpose | NCHW conv+partials | wkb build ------
__global__ __launch_bounds__(256) void k_fused1(const float* __restrict__ x,
        const float* __restrict__ w_vrt, const float* __restrict__ b_vrt,
        const float* __restrict__ w_hrz, const float* __restrict__ b_hrz,
        const float* __restrict__ w_pk, float* __restrict__ ws) {
    __shared__ float tile[32][33];
    __shared__ float red[4][64][4];
    int blk = blockIdx.x, t = threadIdx.x;
    if (blk < 4096) {
        // ---- transpose x (B,C,H,W) -> x_t fp32 [b][i][j][c]
        int j0 = (blk & 3) << 5;
        int bi = blk >> 2;               // b*H + i
        int b = bi >> 7, i = bi & 127;
        int tx = t & 31, ty = t >> 5;
        #pragma unroll
        for (int c = ty; c < 32; c += 8)
            tile[c][tx] = x[(((size_t)b*CCH + c)*HH + i)*WW + j0 + tx];
        __syncthreads();
        float* xt = ws + WS_XT;
        #pragma unroll
        for (int jj = ty; jj < 32; jj += 8)
            xt[(((size_t)bi)*WW + j0 + jj)*CCH + tx] = tile[tx][jj];
    } else if (blk < 4096 + NCONVBLK) {
        // ---- conv: 64 px of row (b,i), cols j0c..j0c+63, from NCHW x
        int cb = blk - 4096;
        int idx0 = cb * 64;
        int b = idx0 >> 14, ij0 = idx0 & 16383, i = ij0 >> 7, j0c = ij0 & 127;
        int px = t & 63;
        int grp = __builtin_amdgcn_readfirstlane(t >> 6);  // wave-uniform ch group
        float v0 = 0.f, v1 = 0.f, h0 = 0.f, h1 = 0.f;
        for (int c8 = 0; c8 < 8; c8++) {
            int c = grp * 8 + c8;
            const float* basec = x + ((size_t)(b*CCH + c))*HH*WW;
            #pragma unroll
            for (int k = 0; k < 7; k++) {
                float wv0 = w_vrt[c*7 + k], wv1 = w_vrt[224 + c*7 + k];
                int gr = i + k - 3;
                if (gr >= 0 && gr < HH) {
                    float xv = basec[(size_t)gr*WW + j0c + px];
                    v0 += wv0 * xv; v1 += wv1 * xv;
                }
                float wh0 = w_hrz[c*7 + k], wh1 = w_hrz[224 + c*7 + k];
                int gc = j0c + px + k - 3;
                if (gc >= 0 && gc < WW) {
                    float xh = basec[(size_t)i*WW + gc];
                    h0 += wh0 * xh; h1 += wh1 * xh;
                }
            }
        }
        red[grp][px][0] = v0; red[grp][px][1] = v1;
        red[grp][px][2] = h0; red[grp][px][3] = h1;
        __syncthreads();
        if (grp == 0) {
            float fv0 = red[0][px][0]+red[1][px][0]+red[2][px][0]+red[3][px][0] + b_vrt[0];
            float fv1 = red[0][px][1]+red[1][px][1]+red[2][px][1]+red[3][px][1] + b_vrt[1];
            float fh0 = red[0][px][2]+red[1][px][2]+red[2][px][2]+red[3][px][2] + b_hrz[0];
            float fh1 = red[0][px][3]+red[1][px][3]+red[2][px][3]+red[3][px][3] + b_hrz[1];
            float4* conv4 = (float4*)(ws + WS_CONV4);
            conv4[idx0 + px] = make_float4(fv0, fv1, fh0, fh1);
            float stv[8] = {fv0, fv1, fh0, fh1, fv0*fv0, fv1*fv1, fh0*fh0, fh1*fh1};
            #pragma unroll
            for (int u = 0; u < 8; u++) {
                float s = stv[u];
                for (int off = 32; off; off >>= 1) s += __shfl_down(s, off);
                if (px == 0) ws[WS_PART + cb*8 + u] = s;   // deterministic, no atomics
            }
        }
    } else {
        // ---- wkb: bf16 W[o][k], k = n*32+c
        unsigned short* wkb = (unsigned short*)(ws + WS_WKB);
        int e = (blk - 4096 - NCONVBLK) * 2048 + t;
        for (int u = 0; u < 8; u++, e += 256) {
            int o = e >> 9, n = (e >> 5) & 15, c = e & 31;
            wkb[o*512 + n*32 + c] = f2bf(w_pk[((o*32 + c) << 4) + n]);
        }
    }
}

// ---------------- K2: reduce partials -> BN affine consts -------------------
__global__ __launch_bounds__(256) void k_prep(
        const float* __restrict__ g_vrt, const float* __restrict__ be_vrt,
        const float* __restrict__ g_hrz, const float* __restrict__ be_hrz,
        float* __restrict__ ws) {
    __shared__ float acc[32][8];
    int t = threadIdx.x;
    int s = t & 7, chunk = t >> 3;          // 32 chunks of 64 blocks
    float sum = 0.f;
    for (int m = 0; m < 64; m++)
        sum += ws[WS_PART + (size_t)(chunk*64 + m)*8 + s];
    acc[chunk][s] = sum;
    __syncthreads();
    if (t < 8) {
        float tot = 0.f;
        #pragma unroll
        for (int c = 0; c < 32; c++) tot += acc[c][t];
        acc[0][t] = tot;
    }
    __syncthreads();
    if (t < 4) {
        const float cnt = (float)NPIX;
        float mean = acc[0][t] / cnt;
        float var  = acc[0][4 + t] / cnt - mean * mean;
        float gamma = (t < 2) ? g_vrt[t] : g_hrz[t - 2];
        float beta  = (t < 2) ? be_vrt[t] : be_hrz[t - 2];
        float a = gamma * rsqrtf(var + 1e-5f);
        ws[WS_BNAB + t]     = a;
        ws[WS_BNAB + 4 + t] = beta - mean * a;
    }
}

// ---- general 2-sample path (only needed for n=11, n=15 clip edge cases) ----
__device__ __forceinline__ short8 sample_frag(const unsigned short* tile,
        const float* xc8, const float* gbv, float fi, float fj, int n,
        float prx, float pry, int i0, int j0, int quad) {
    float mx = 0.f, my = 0.f;
    if (n < 4)       mx = -gbv[0];
    else if (n < 8)  my =  gbv[3];
    else if (n < 12) mx =  gbv[1];
    else             my = -gbv[2];
    float px = fi + prx + mx;
    float py = fj + pry + my;
    float qlx = floorf(px), qly = floorf(py);
    int qlxi = min(max((int)qlx, 0), HWP);
    int qlyi = min(max((int)qly, 0), HWP);
    int qrxi = min(max((int)qlx + 1, 0), HWP);
    int qryi = min(max((int)qly + 1, 0), HWP);
    float pxc = fminf(fmaxf(px, 0.f), (float)HWP);
    float pyc = fminf(fmaxf(py, 0.f), (float)HWP);
    float glt = (1.f + ((float)qlxi - pxc)) * (1.f + ((float)qlyi - pyc));
    float grb = (1.f - ((float)qrxi - pxc)) * (1.f - ((float)qryi - pyc));
    float nglt = -glt, ngrb = -grb;
    // edge pad: x_pad[a] = x[clamp(a-2,0,127)]
    int ltr = min(max(qlxi - 2, 0), HH - 1), ltc = min(max(qlyi - 2, 0), WW - 1);
    int rbr = min(max(qrxi - 2, 0), HH - 1), rbc = min(max(qryi - 2, 0), WW - 1);
    int lt_off = (ltr - i0 + 4)*1600 + (ltc - j0 + 4)*40 + quad*8;
    int rb_off = (rbr - i0 + 4)*1600 + (rbc - j0 + 4)*40 + quad*8;
    uint4 lw = *(const uint4*)(tile + lt_off);
    uint4 rw = *(const uint4*)(tile + rb_off);
    float d0 = fmaf(nglt, bflo(lw.x), fmaf(ngrb, bflo(rw.x), xc8[0]));
    float d1 = fmaf(nglt, bfhi(lw.x), fmaf(ngrb, bfhi(rw.x), xc8[1]));
    float d2 = fmaf(nglt, bflo(lw.y), fmaf(ngrb, bflo(rw.y), xc8[2]));
    float d3 = fmaf(nglt, bfhi(lw.y), fmaf(ngrb, bfhi(rw.y), xc8[3]));
    float d4 = fmaf(nglt, bflo(lw.z), fmaf(ngrb, bflo(rw.z), xc8[4]));
    float d5 = fmaf(nglt, bfhi(lw.z), fmaf(ngrb, bfhi(rw.z), xc8[5]));
    float d6 = fmaf(nglt, bflo(lw.w), fmaf(ngrb, bflo(rw.w), xc8[6]));
    float d7 = fmaf(nglt, bfhi(lw.w), fmaf(ngrb, bfhi(rw.w), xc8[7]));
    uint4 bw;
    bw.x = cvtpk(d0, d1); bw.y = cvtpk(d2, d3);
    bw.z = cvtpk(d4, d5); bw.w = cvtpk(d6, d7);
    return *(short8*)&bw;
}

// ---- fast 1-sample path: the grb term is exactly 0 for n notin {11,15} ----
// (one coordinate per ring-group is integral; q_rb - p == 1 on that axis)
__device__ __forceinline__ void frac_setup(float pm, float& ng, int& m) {
    float qf = floorf(pm);
    int qi = min(max((int)qf, 0), HWP);
    float pmc = fminf(fmaxf(pm, 0.f), (float)HWP);
    ng = pmc - (float)qi - 1.f;                 // = -(1 + qi - pmc) = -g_lt
    m = min(max(qi - 2, 0), HH - 1);            // unpadded moving coord
}
__device__ __forceinline__ short8 samp1(const unsigned short* tile,
        const float* xc8, float ng, int off) {
    uint4 lw = *(const uint4*)(tile + off);
    float d0 = fmaf(ng, bflo(lw.x), xc8[0]);
    float d1 = fmaf(ng, bfhi(lw.x), xc8[1]);
    float d2 = fmaf(ng, bflo(lw.y), xc8[2]);
    float d3 = fmaf(ng, bfhi(lw.y), xc8[3]);
    float d4 = fmaf(ng, bflo(lw.z), xc8[4]);
    float d5 = fmaf(ng, bfhi(lw.z), xc8[5]);
    float d6 = fmaf(ng, bflo(lw.w), xc8[6]);
    float d7 = fmaf(ng, bfhi(lw.w), xc8[7]);
    uint4 bw;
    bw.x = cvtpk(d0, d1); bw.y = cvtpk(d2, d3);
    bw.z = cvtpk(d4, d5); bw.w = cvtpk(d6, d7);
    return *(short8*)&bw;
}

// ---------------- K3: MFMA, 2 pixel-tiles per wave, weight prefetch ---------
// 1024 blocks x 256 thr. Block = (b, rows i0..i0+3, cols j0..j0+31) = 128 px.
// Wave w (0..3): row ir = i0+w; tile A = cols j0+pl, tile B = cols j0+16+pl.
__global__ __launch_bounds__(256, 4) void k_main(const float* __restrict__ ws,
        const float* __restrict__ b_pk, float* __restrict__ out) {
    __shared__ unsigned short tile[TILE_USH];     // 38400 B
    const float* xt   = ws + WS_XT;
    const float* bnab = ws + WS_BNAB;
    const unsigned short* wkb = (const unsigned short*)(ws + WS_WKB);
    const float prfx[16] = {-2,-2,-2,-2, -2,-1, 0, 1,  2, 2, 2, 2, -1, 0, 1, 2};
    const float prfy[16] = {-2,-1, 0, 1,  2, 2, 2, 2, -1, 0, 1, 2, -2,-2,-2,-2};
    // integer-axis per-n offset (col for groups 0,2; row for groups 1,3)
    const int ioffs[16]  = {-2,-1, 0, 1, -2,-1, 0, 1, -1, 0, 1, 2, -1, 0, 1, 2};

    int t = threadIdx.x;
    int blk = blockIdx.x;                 // b(3b) | ig(5b) | jh(2b)
    int b = blk >> 7;
    int i0 = ((blk >> 2) & 31) * 4;
    int j0 = (blk & 3) * 32;

    // ---- coalesced tile load (fp32 -> bf16, edge clamp), 12 rows x 40 cols
    for (int s = t; s < 12*40*4; s += 256) {
        int q = s & 3, cc = (s >> 2) % 40, r = (s >> 2) / 40;
        int gr = min(max(i0 - 4 + r, 0), HH - 1);
        int gc = min(max(j0 - 4 + cc, 0), WW - 1);
        const float4* src = (const float4*)(xt + (((size_t)(b*HH + gr))*WW + gc)*CCH + q*8);
        float4 f0 = src[0], f1 = src[1];
        uint4 v;
        v.x = cvtpk(f0.x, f0.y); v.y = cvtpk(f0.z, f0.w);
        v.z = cvtpk(f1.x, f1.y); v.w = cvtpk(f1.z, f1.w);
        *(uint4*)(tile + ((r*40 + cc)*5 + q)*8) = v;
    }
    __syncthreads();

    int w = t >> 6, pl = t & 15, quad = (t >> 4) & 3;
    int ir = i0 + w;
    int pjA = j0 + pl, pjB = j0 + 16 + pl;
    int pixA = (b << 14) + ir * WW + pjA;
    int pixB = pixA + 16;
    int q8 = quad * 8;

    // fp32 center channels for both pixels (coalesced)
    float xcA[8], xcB[8];
    {
        const float4* xpA = (const float4*)(xt + (size_t)pixA * CCH + q8);
        float4 v0 = xpA[0], v1 = xpA[1];
        xcA[0]=v0.x; xcA[1]=v0.y; xcA[2]=v0.z; xcA[3]=v0.w;
        xcA[4]=v1.x; xcA[5]=v1.y; xcA[6]=v1.z; xcA[7]=v1.w;
        const float4* xpB = (const float4*)(xt + (size_t)pixB * CCH + q8);
        float4 u0 = xpB[0], u1 = xpB[1];
        xcB[0]=u0.x; xcB[1]=u0.y; xcB[2]=u0.z; xcB[3]=u0.w;
        xcB[4]=u1.x; xcB[5]=u1.y; xcB[6]=u1.z; xcB[7]=u1.w;
    }
    // gates for both pixels
    const float4* conv4 = (const float4*)(ws + WS_CONV4);
    float4 cvA = conv4[pixA], cvB = conv4[pixB];
    float gbvA[4], gbvB[4];
    gbvA[0] = 2.f / (1.f + expf(-(cvA.x * bnab[0] + bnab[4])));
    gbvA[1] = 2.f / (1.f + expf(-(cvA.y * bnab[1] + bnab[5])));
    gbvA[2] = 2.f / (1.f + expf(-(cvA.z * bnab[2] + bnab[6])));
    gbvA[3] = 2.f / (1.f + expf(-(cvA.w * bnab[3] + bnab[7])));
    gbvB[0] = 2.f / (1.f + expf(-(cvB.x * bnab[0] + bnab[4])));
    gbvB[1] = 2.f / (1.f + expf(-(cvB.y * bnab[1] + bnab[5])));
    gbvB[2] = 2.f / (1.f + expf(-(cvB.z * bnab[2] + bnab[6])));
    gbvB[3] = 2.f / (1.f + expf(-(cvB.w * bnab[3] + bnab[7])));

    f32x4 accA0 = {0.f,0.f,0.f,0.f}, accA1 = {0.f,0.f,0.f,0.f};
    f32x4 accB0 = {0.f,0.f,0.f,0.f}, accB1 = {0.f,0.f,0.f,0.f};
    float fi = (float)ir + 2.f;
    float fjA = (float)pjA + 2.f, fjB = (float)pjB + 2.f;

    // weight prefetch pipeline (A-frags shared by both pixel tiles)
    short8 a0 = *(const short8*)(wkb + (size_t)pl * 512 + q8);
    short8 a1 = *(const short8*)(wkb + (size_t)(pl + 16) * 512 + q8);

    // per-group fractional-axis state (recomputed at n = 0,4,8,12)
    float ngA_ = 0.f, ngB_ = 0.f;
    int baseA_ = 0, baseB_ = 0;

    #pragma unroll
    for (int n = 0; n < 16; n++) {
        short8 na0 = a0, na1 = a1;
        if (n < 15) {
            na0 = *(const short8*)(wkb + (size_t)pl * 512 + (n+1)*32 + q8);
            na1 = *(const short8*)(wkb + (size_t)(pl + 16) * 512 + (n+1)*32 + q8);
        }
        if ((n & 3) == 0) {            // group boundary: frac coord constant over 4 n's
            int g = n >> 2;
            float pmA, pmB;
            if (g == 0)      { pmA = (fi  - 2.f) - gbvA[0]; pmB = (fi  - 2.f) - gbvB[0]; }
            else if (g == 1) { pmA = (fjA + 2.f) + gbvA[3]; pmB = (fjB + 2.f) + gbvB[3]; }
            else if (g == 2) { pmA = (fi  + 2.f) + gbvA[1]; pmB = (fi  + 2.f) + gbvB[1]; }
            else             { pmA = (fjA - 2.f) - gbvA[2]; pmB = (fjB - 2.f) - gbvB[2]; }
            int mA, mB;
            frac_setup(pmA, ngA_, mA);
            frac_setup(pmB, ngB_, mB);
            if ((g & 1) == 0) {        // moving axis = row
                baseA_ = (mA - i0 + 4)*1600 + q8;
                baseB_ = (mB - i0 + 4)*1600 + q8;
            } else {                   // moving axis = col
                baseA_ = (mA - j0 + 4)*40 + q8;
                baseB_ = (mB - j0 + 4)*40 + q8;
            }
        }
        short8 bfA, bfB;
        if (n == 11 || n == 15) {      // clip-edge cases: grb can be nonzero
            bfA = sample_frag(tile, xcA, gbvA, fi, fjA, n, prfx[n], prfy[n], i0, j0, quad);
            bfB = sample_frag(tile, xcB, gbvB, fi, fjB, n, prfx[n], prfy[n], i0, j0, quad);
        } else {
            int io = ioffs[n];
            int offA, offB;
            if (((n >> 2) & 1) == 0) { // int axis = col
                int cA = min(max(pjA + io, 0), WW - 1);
                int cB = min(max(pjB + io, 0), WW - 1);
                offA = baseA_ + (cA - j0 + 4)*40;
                offB = baseB_ + (cB - j0 + 4)*40;
            } else {                   // int axis = row (shared by A and B)
                int r  = min(max(ir + io, 0), HH - 1);
                int rt = (r - i0 + 4)*1600;
                offA = baseA_ + rt;
                offB = baseB_ + rt;
            }
            bfA = samp1(tile, xcA, ngA_, offA);
            bfB = samp1(tile, xcB, ngB_, offB);
        }
        accA0 = __builtin_amdgcn_mfma_f32_16x16x32_bf16(a0, bfA, accA0, 0, 0, 0);
        accA1 = __builtin_amdgcn_mfma_f32_16x16x32_bf16(a1, bfA, accA1, 0, 0, 0);
        accB0 = __builtin_amdgcn_mfma_f32_16x16x32_bf16(a0, bfB, accB0, 0, 0, 0);
        accB1 = __builtin_amdgcn_mfma_f32_16x16x32_bf16(a1, bfB, accB1, 0, 0, 0);
        a0 = na0; a1 = na1;
    }
    // epilogue: col = pl (pixel), row = quad*4+reg (out channel)
    float* opA = out + (size_t)b * (OUTC*HH*WW) + ir * WW + pjA;
    float* opB = opA + 16;
    #pragma unroll
    for (int r = 0; r < 4; r++) {
        int o = quad*4 + r;
        float bo = b_pk[o], bo16 = b_pk[o + 16];
        opA[(size_t)o * (HH*WW)]        = accA0[r] + bo;
        opA[(size_t)(o + 16) * (HH*WW)] = accA1[r] + bo16;
        opB[(size_t)o * (HH*WW)]        = accB0[r] + bo;
        opB[(size_t)(o + 16) * (HH*WW)] = accB1[r] + bo16;
    }
}

extern "C" void kernel_launch(void* const* d_in, const int* in_sizes, int n_in,
                              void* d_out, int out_size, void* d_ws, size_t ws_size,
                              hipStream_t stream) {
    const float* x      = (const float*)d_in[0];
    const float* w_vrt  = (const float*)d_in[1];
    const float* b_vrt  = (const float*)d_in[2];
    const float* g_vrt  = (const float*)d_in[3];
    const float* be_vrt = (const float*)d_in[4];
    const float* w_hrz  = (const float*)d_in[5];
    const float* b_hrz  = (const float*)d_in[6];
    const float* g_hrz  = (const float*)d_in[7];
    const float* be_hrz = (const float*)d_in[8];
    const float* w_pk   = (const float*)d_in[9];
    const float* b_pk   = (const float*)d_in[10];
    float* ws  = (float*)d_ws;
    float* out = (float*)d_out;

    k_fused1<<<4096 + NCONVBLK + 8, 256, 0, stream>>>(x, w_vrt, b_vrt, w_hrz, b_hrz, w_pk, ws);
    k_prep<<<1, 256, 0, stream>>>(g_vrt, be_vrt, g_hrz, be_hrz, ws);
    k_main<<<1024, 256, 0, stream>>>(ws, b_pk, out);
}

// Round 2
// 150.883 us; speedup vs baseline: 1.0401x; 1.0009x over previous
//
#include <hip/hip_runtime.h>
#include <math.h>

#define BB 8
#define CCH 32
#define HH 128
#define WW 128
#define OUTC 32
#define NPIX (BB*HH*WW)          // 131072
#define HWP 131                   // padded-coord clamp limit
#define NCONVBLK 2048             // conv blocks (64 px each)

// workspace layout (float offsets) — ~10.6 MB
#define WS_XTB   0                                   // bf16 x_t [b][i][j][c], 8.39 MB
#define WS_CONV4 (BB*HH*WW*CCH/2)                    // pre-BN conv, 4 f/px, 2 MB
#define WS_PART  (WS_CONV4 + BB*HH*WW*4)             // 2048*8 f per-block stats partials
#define WS_WKB   (WS_PART + NCONVBLK*8)              // 16384 ushort bf16 W[o][k], k=n*32+c

// k_main LDS tile: rows i0-4..i0+7 (12), cols j0-4..j0+35 (40), 5-group padding
// offset(r,cc,q) = ((r*40+cc)*5 + q)*8 ushorts = r*1600 + cc*40 + q*8
#define TILE_USH (12*40*5*8)                         // 19200 ushorts = 38400 B

typedef __attribute__((ext_vector_type(8))) short short8;
typedef __attribute__((ext_vector_type(4))) float f32x4;

__device__ __forceinline__ unsigned short f2bf(float f) {
    unsigned u = __float_as_uint(f);
    unsigned r = (u + 0x7FFFu + ((u >> 16) & 1u)) >> 16;   // RTNE
    return (unsigned short)r;
}
// hw packed RTNE f32->bf16x2 (same rounding as f2bf); no builtin on gfx950
__device__ __forceinline__ unsigned cvtpk(float lo, float hi) {
    unsigned r;
    asm("v_cvt_pk_bf16_f32 %0, %1, %2" : "=v"(r) : "v"(lo), "v"(hi));
    return r;
}
__device__ __forceinline__ float bflo(unsigned w) { return __uint_as_float(w << 16); }
__device__ __forceinline__ float bfhi(unsigned w) { return __uint_as_float(w & 0xFFFF0000u); }

// ---------------- K1: fused transpose->bf16 | NCHW conv+partials | wkb ------
__global__ __launch_bounds__(256) void k_fused1(const float* __restrict__ x,
        const float* __restrict__ w_vrt, const float* __restrict__ b_vrt,
        const float* __restrict__ w_hrz, const float* __restrict__ b_hrz,
        const float* __restrict__ w_pk, float* __restrict__ ws) {
    __shared__ float tile[32][33];
    __shared__ float red[4][64][4];
    int blk = blockIdx.x, t = threadIdx.x;
    if (blk < 4096) {
        // ---- transpose x (B,C,H,W) -> x_t bf16 [b][i][j][c] (packed pairs)
        int j0 = (blk & 3) << 5;
        int bi = blk >> 2;               // b*H + i
        int b = bi >> 7, i = bi & 127;
        int tx = t & 31, ty = t >> 5;
        #pragma unroll
        for (int c = ty; c < 32; c += 8)
            tile[c][tx] = x[(((size_t)b*CCH + c)*HH + i)*WW + j0 + tx];
        __syncthreads();
        unsigned* xtb4 = (unsigned*)(ws + WS_XTB);   // 1 dword = 2 channels
        int cp = t & 15, jy = t >> 4;
        #pragma unroll
        for (int u = 0; u < 2; u++) {
            int jj = jy + u*16;
            unsigned v = cvtpk(tile[2*cp][jj], tile[2*cp + 1][jj]);
            xtb4[((size_t)bi*WW + j0 + jj)*16 + cp] = v;
        }
    } else if (blk < 4096 + NCONVBLK) {
        // ---- conv: 64 px of row (b,i), cols j0c..j0c+63, from NCHW x
        int cb = blk - 4096;
        int idx0 = cb * 64;
        int b = idx0 >> 14, ij0 = idx0 & 16383, i = ij0 >> 7, j0c = ij0 & 127;
        int px = t & 63;
        int grp = __builtin_amdgcn_readfirstlane(t >> 6);  // wave-uniform ch group
        float v0 = 0.f, v1 = 0.f, h0 = 0.f, h1 = 0.f;
        for (int c8 = 0; c8 < 8; c8++) {
            int c = grp * 8 + c8;
            const float* basec = x + ((size_t)(b*CCH + c))*HH*WW;
            #pragma unroll
            for (int k = 0; k < 7; k++) {
                float wv0 = w_vrt[c*7 + k], wv1 = w_vrt[224 + c*7 + k];
                int gr = i + k - 3;
                if (gr >= 0 && gr < HH) {
                    float xv = basec[(size_t)gr*WW + j0c + px];
                    v0 += wv0 * xv; v1 += wv1 * xv;
                }
                float wh0 = w_hrz[c*7 + k], wh1 = w_hrz[224 + c*7 + k];
                int gc = j0c + px + k - 3;
                if (gc >= 0 && gc < WW) {
                    float xh = basec[(size_t)i*WW + gc];
                    h0 += wh0 * xh; h1 += wh1 * xh;
                }
            }
        }
        red[grp][px][0] = v0; red[grp][px][1] = v1;
        red[grp][px][2] = h0; red[grp][px][3] = h1;
        __syncthreads();
        if (grp == 0) {
            float fv0 = red[0][px][0]+red[1][px][0]+red[2][px][0]+red[3][px][0] + b_vrt[0];
            float fv1 = red[0][px][1]+red[1][px][1]+red[2][px][1]+red[3][px][1] + b_vrt[1];
            float fh0 = red[0][px][2]+red[1][px][2]+red[2][px][2]+red[3][px][2] + b_hrz[0];
            float fh1 = red[0][px][3]+red[1][px][3]+red[2][px][3]+red[3][px][3] + b_hrz[1];
            float4* conv4 = (float4*)(ws + WS_CONV4);
            conv4[idx0 + px] = make_float4(fv0, fv1, fh0, fh1);
            float stv[8] = {fv0, fv1, fh0, fh1, fv0*fv0, fv1*fv1, fh0*fh0, fh1*fh1};
            #pragma unroll
            for (int u = 0; u < 8; u++) {
                float s = stv[u];
                for (int off = 32; off; off >>= 1) s += __shfl_down(s, off);
                if (px == 0) ws[WS_PART + cb*8 + u] = s;   // deterministic, no atomics
            }
        }
    } else {
        // ---- wkb: bf16 W[o][k], k = n*32+c
        unsigned short* wkb = (unsigned short*)(ws + WS_WKB);
        int e = (blk - 4096 - NCONVBLK) * 2048 + t;
        for (int u = 0; u < 8; u++, e += 256) {
            int o = e >> 9, n = (e >> 5) & 15, c = e & 31;
            wkb[o*512 + n*32 + c] = f2bf(w_pk[((o*32 + c) << 4) + n]);
        }
    }
}

// ---- general 2-sample path (only needed for n=11, n=15 clip edge cases) ----
__device__ __forceinline__ short8 sample_frag(const unsigned short* tile,
        const float* xc8, const float* gbv, float fi, float fj, int n,
        float prx, float pry, int i0, int j0, int quad) {
    float mx = 0.f, my = 0.f;
    if (n < 4)       mx = -gbv[0];
    else if (n < 8)  my =  gbv[3];
    else if (n < 12) mx =  gbv[1];
    else             my = -gbv[2];
    float px = fi + prx + mx;
    float py = fj + pry + my;
    float qlx = floorf(px), qly = floorf(py);
    int qlxi = min(max((int)qlx, 0), HWP);
    int qlyi = min(max((int)qly, 0), HWP);
    int qrxi = min(max((int)qlx + 1, 0), HWP);
    int qryi = min(max((int)qly + 1, 0), HWP);
    float pxc = fminf(fmaxf(px, 0.f), (float)HWP);
    float pyc = fminf(fmaxf(py, 0.f), (float)HWP);
    float glt = (1.f + ((float)qlxi - pxc)) * (1.f + ((float)qlyi - pyc));
    float grb = (1.f - ((float)qrxi - pxc)) * (1.f - ((float)qryi - pyc));
    float nglt = -glt, ngrb = -grb;
    // edge pad: x_pad[a] = x[clamp(a-2,0,127)]
    int ltr = min(max(qlxi - 2, 0), HH - 1), ltc = min(max(qlyi - 2, 0), WW - 1);
    int rbr = min(max(qrxi - 2, 0), HH - 1), rbc = min(max(qryi - 2, 0), WW - 1);
    int lt_off = (ltr - i0 + 4)*1600 + (ltc - j0 + 4)*40 + quad*8;
    int rb_off = (rbr - i0 + 4)*1600 + (rbc - j0 + 4)*40 + quad*8;
    uint4 lw = *(const uint4*)(tile + lt_off);
    uint4 rw = *(const uint4*)(tile + rb_off);
    float d0 = fmaf(nglt, bflo(lw.x), fmaf(ngrb, bflo(rw.x), xc8[0]));
    float d1 = fmaf(nglt, bfhi(lw.x), fmaf(ngrb, bfhi(rw.x), xc8[1]));
    float d2 = fmaf(nglt, bflo(lw.y), fmaf(ngrb, bflo(rw.y), xc8[2]));
    float d3 = fmaf(nglt, bfhi(lw.y), fmaf(ngrb, bfhi(rw.y), xc8[3]));
    float d4 = fmaf(nglt, bflo(lw.z), fmaf(ngrb, bflo(rw.z), xc8[4]));
    float d5 = fmaf(nglt, bfhi(lw.z), fmaf(ngrb, bfhi(rw.z), xc8[5]));
    float d6 = fmaf(nglt, bflo(lw.w), fmaf(ngrb, bflo(rw.w), xc8[6]));
    float d7 = fmaf(nglt, bfhi(lw.w), fmaf(ngrb, bfhi(rw.w), xc8[7]));
    uint4 bw;
    bw.x = cvtpk(d0, d1); bw.y = cvtpk(d2, d3);
    bw.z = cvtpk(d4, d5); bw.w = cvtpk(d6, d7);
    return *(short8*)&bw;
}

// ---- fast 1-sample path: the grb term is exactly 0 for n notin {11,15} ----
// (one coordinate per ring-group is integral; q_rb - p == 1 on that axis)
__device__ __forceinline__ void frac_setup(float pm, float& ng, int& m) {
    float qf = floorf(pm);
    int qi = min(max((int)qf, 0), HWP);
    float pmc = fminf(fmaxf(pm, 0.f), (float)HWP);
    ng = pmc - (float)qi - 1.f;                 // = -(1 + qi - pmc) = -g_lt
    m = min(max(qi - 2, 0), HH - 1);            // unpadded moving coord
}
__device__ __forceinline__ short8 samp1(const unsigned short* tile,
        const float* xc8, float ng, int off) {
    uint4 lw = *(const uint4*)(tile + off);
    float d0 = fmaf(ng, bflo(lw.x), xc8[0]);
    float d1 = fmaf(ng, bfhi(lw.x), xc8[1]);
    float d2 = fmaf(ng, bflo(lw.y), xc8[2]);
    float d3 = fmaf(ng, bfhi(lw.y), xc8[3]);
    float d4 = fmaf(ng, bflo(lw.z), xc8[4]);
    float d5 = fmaf(ng, bfhi(lw.z), xc8[5]);
    float d6 = fmaf(ng, bflo(lw.w), xc8[6]);
    float d7 = fmaf(ng, bfhi(lw.w), xc8[7]);
    uint4 bw;
    bw.x = cvtpk(d0, d1); bw.y = cvtpk(d2, d3);
    bw.z = cvtpk(d4, d5); bw.w = cvtpk(d6, d7);
    return *(short8*)&bw;
}

// ---------------- K2: bn-reduce + MFMA main (k_prep folded in) --------------
// 1024 blocks x 256 thr. Block = (b, rows i0..i0+3, cols j0..j0+31) = 128 px.
// Wave w (0..3): row ir = i0+w; tile A = cols j0+pl, tile B = cols j0+16+pl.
__global__ __launch_bounds__(256, 4) void k_main(const float* __restrict__ ws,
        const float* __restrict__ x,
        const float* __restrict__ g_vrt, const float* __restrict__ be_vrt,
        const float* __restrict__ g_hrz, const float* __restrict__ be_hrz,
        const float* __restrict__ b_pk, float* __restrict__ out) {
    __shared__ unsigned short tile[TILE_USH];     // 38400 B
    __shared__ float racc[32][8];                 // 1024 B
    __shared__ float bnab_s[8];
    const unsigned short* xtb = (const unsigned short*)(ws + WS_XTB);
    const unsigned short* wkb = (const unsigned short*)(ws + WS_WKB);
    const float* part = ws + WS_PART;
    const float prfx[16] = {-2,-2,-2,-2, -2,-1, 0, 1,  2, 2, 2, 2, -1, 0, 1, 2};
    const float prfy[16] = {-2,-1, 0, 1,  2, 2, 2, 2, -1, 0, 1, 2, -2,-2,-2,-2};
    // integer-axis per-n offset (col for groups 0,2; row for groups 1,3)
    const int ioffs[16]  = {-2,-1, 0, 1, -2,-1, 0, 1, -1, 0, 1, 2, -1, 0, 1, 2};

    int t = threadIdx.x;
    // XCD-aware bijective swizzle (1024 % 8 == 0): one batch image per XCD
    int blk = ((blockIdx.x & 7) << 7) | (blockIdx.x >> 3);
    int b = blk >> 7;
    int i0 = ((blk >> 2) & 31) * 4;
    int j0 = (blk & 3) * 32;

    // ---- coalesced bf16 tile copy (no conversion), 12 rows x 40 cols
    for (int s = t; s < 12*40*4; s += 256) {
        int q = s & 3, cc = (s >> 2) % 40, r = (s >> 2) / 40;
        int gr = min(max(i0 - 4 + r, 0), HH - 1);
        int gc = min(max(j0 - 4 + cc, 0), WW - 1);
        uint4 v = *(const uint4*)(xtb + (((size_t)(b*HH + gr))*WW + gc)*CCH + q*8);
        *(uint4*)(tile + ((r*40 + cc)*5 + q)*8) = v;
    }
    // ---- bn partial reduce stage 1 (identical summation order to old k_prep)
    {
        int s8 = t & 7, chunk = t >> 3;
        float sum = 0.f;
        #pragma unroll 8
        for (int m = 0; m < 64; m++)
            sum += part[(size_t)(chunk*64 + m)*8 + s8];
        racc[chunk][s8] = sum;
    }
    __syncthreads();
    if (t < 8) {
        float tot = 0.f;
        #pragma unroll
        for (int c = 0; c < 32; c++) tot += racc[c][t];
        racc[0][t] = tot;
    }
    __syncthreads();
    if (t < 4) {
        const float cnt = (float)NPIX;
        float mean = racc[0][t] / cnt;
        float var  = racc[0][4 + t] / cnt - mean * mean;
        float gamma = (t < 2) ? g_vrt[t] : g_hrz[t - 2];
        float beta  = (t < 2) ? be_vrt[t] : be_hrz[t - 2];
        float a = gamma * rsqrtf(var + 1e-5f);
        bnab_s[t]     = a;
        bnab_s[4 + t] = beta - mean * a;
    }
    __syncthreads();

    int w = t >> 6, pl = t & 15, quad = (t >> 4) & 3;
    int ir = i0 + w;
    int pjA = j0 + pl, pjB = j0 + 16 + pl;
    int pixA = (b << 14) + ir * WW + pjA;
    int pixB = pixA + 16;
    int q8 = quad * 8;

    // fp32 center channels for both pixels, straight from NCHW x (exact)
    float xcA[8], xcB[8];
    {
        const float* xb = x + (size_t)b * CCH * HH * WW + (size_t)ir * WW;
        #pragma unroll
        for (int k = 0; k < 8; k++) {
            const float* p = xb + (size_t)(q8 + k) * (HH * WW);
            xcA[k] = p[pjA];
            xcB[k] = p[pjB];
        }
    }
    // gates for both pixels
    const float4* conv4 = (const float4*)(ws + WS_CONV4);
    float4 cvA = conv4[pixA], cvB = conv4[pixB];
    float gbvA[4], gbvB[4];
    gbvA[0] = 2.f / (1.f + expf(-(cvA.x * bnab_s[0] + bnab_s[4])));
    gbvA[1] = 2.f / (1.f + expf(-(cvA.y * bnab_s[1] + bnab_s[5])));
    gbvA[2] = 2.f / (1.f + expf(-(cvA.z * bnab_s[2] + bnab_s[6])));
    gbvA[3] = 2.f / (1.f + expf(-(cvA.w * bnab_s[3] + bnab_s[7])));
    gbvB[0] = 2.f / (1.f + expf(-(cvB.x * bnab_s[0] + bnab_s[4])));
    gbvB[1] = 2.f / (1.f + expf(-(cvB.y * bnab_s[1] + bnab_s[5])));
    gbvB[2] = 2.f / (1.f + expf(-(cvB.z * bnab_s[2] + bnab_s[6])));
    gbvB[3] = 2.f / (1.f + expf(-(cvB.w * bnab_s[3] + bnab_s[7])));

    f32x4 accA0 = {0.f,0.f,0.f,0.f}, accA1 = {0.f,0.f,0.f,0.f};
    f32x4 accB0 = {0.f,0.f,0.f,0.f}, accB1 = {0.f,0.f,0.f,0.f};
    float fi = (float)ir + 2.f;
    float fjA = (float)pjA + 2.f, fjB = (float)pjB + 2.f;

    // weight prefetch pipeline (A-frags shared by both pixel tiles)
    short8 a0 = *(const short8*)(wkb + (size_t)pl * 512 + q8);
    short8 a1 = *(const short8*)(wkb + (size_t)(pl + 16) * 512 + q8);

    // per-group fractional-axis state (recomputed at n = 0,4,8,12)
    float ngA_ = 0.f, ngB_ = 0.f;
    int baseA_ = 0, baseB_ = 0;

    #pragma unroll
    for (int n = 0; n < 16; n++) {
        short8 na0 = a0, na1 = a1;
        if (n < 15) {
            na0 = *(const short8*)(wkb + (size_t)pl * 512 + (n+1)*32 + q8);
            na1 = *(const short8*)(wkb + (size_t)(pl + 16) * 512 + (n+1)*32 + q8);
        }
        if ((n & 3) == 0) {            // group boundary: frac coord constant over 4 n's
            int g = n >> 2;
            float pmA, pmB;
            if (g == 0)      { pmA = (fi  - 2.f) - gbvA[0]; pmB = (fi  - 2.f) - gbvB[0]; }
            else if (g == 1) { pmA = (fjA + 2.f) + gbvA[3]; pmB = (fjB + 2.f) + gbvB[3]; }
            else if (g == 2) { pmA = (fi  + 2.f) + gbvA[1]; pmB = (fi  + 2.f) + gbvB[1]; }
            else             { pmA = (fjA - 2.f) - gbvA[2]; pmB = (fjB - 2.f) - gbvB[2]; }
            int mA, mB;
            frac_setup(pmA, ngA_, mA);
            frac_setup(pmB, ngB_, mB);
            if ((g & 1) == 0) {        // moving axis = row
                baseA_ = (mA - i0 + 4)*1600 + q8;
                baseB_ = (mB - i0 + 4)*1600 + q8;
            } else {                   // moving axis = col
                baseA_ = (mA - j0 + 4)*40 + q8;
                baseB_ = (mB - j0 + 4)*40 + q8;
            }
        }
        short8 bfA, bfB;
        if (n == 11 || n == 15) {      // clip-edge cases: grb can be nonzero
            bfA = sample_frag(tile, xcA, gbvA, fi, fjA, n, prfx[n], prfy[n], i0, j0, quad);
            bfB = sample_frag(tile, xcB, gbvB, fi, fjB, n, prfx[n], prfy[n], i0, j0, quad);
        } else {
            int io = ioffs[n];
            int offA, offB;
            if (((n >> 2) & 1) == 0) { // int axis = col
                int cA = min(max(pjA + io, 0), WW - 1);
                int cB = min(max(pjB + io, 0), WW - 1);
                offA = baseA_ + (cA - j0 + 4)*40;
                offB = baseB_ + (cB - j0 + 4)*40;
            } else {                   // int axis = row (shared by A and B)
                int r  = min(max(ir + io, 0), HH - 1);
                int rt = (r - i0 + 4)*1600;
                offA = baseA_ + rt;
                offB = baseB_ + rt;
            }
            bfA = samp1(tile, xcA, ngA_, offA);
            bfB = samp1(tile, xcB, ngB_, offB);
        }
        accA0 = __builtin_amdgcn_mfma_f32_16x16x32_bf16(a0, bfA, accA0, 0, 0, 0);
        accA1 = __builtin_amdgcn_mfma_f32_16x16x32_bf16(a1, bfA, accA1, 0, 0, 0);
        accB0 = __builtin_amdgcn_mfma_f32_16x16x32_bf16(a0, bfB, accB0, 0, 0, 0);
        accB1 = __builtin_amdgcn_mfma_f32_16x16x32_bf16(a1, bfB, accB1, 0, 0, 0);
        a0 = na0; a1 = na1;
    }
    // epilogue: col = pl (pixel), row = quad*4+reg (out channel)
    float* opA = out + (size_t)b * (OUTC*HH*WW) + ir * WW + pjA;
    float* opB = opA + 16;
    #pragma unroll
    for (int r = 0; r < 4; r++) {
        int o = quad*4 + r;
        float bo = b_pk[o], bo16 = b_pk[o + 16];
        opA[(size_t)o * (HH*WW)]        = accA0[r] + bo;
        opA[(size_t)(o + 16) * (HH*WW)] = accA1[r] + bo16;
        opB[(size_t)o * (HH*WW)]        = accB0[r] + bo;
        opB[(size_t)(o + 16) * (HH*WW)] = accB1[r] + bo16;
    }
}

extern "C" void kernel_launch(void* const* d_in, const int* in_sizes, int n_in,
                              void* d_out, int out_size, void* d_ws, size_t ws_size,
                              hipStream_t stream) {
    const float* x      = (const float*)d_in[0];
    const float* w_vrt  = (const float*)d_in[1];
    const float* b_vrt  = (const float*)d_in[2];
    const float* g_vrt  = (const float*)d_in[3];
    const float* be_vrt = (const float*)d_in[4];
    const float* w_hrz  = (const float*)d_in[5];
    const float* b_hrz  = (const float*)d_in[6];
    const float* g_hrz  = (const float*)d_in[7];
    const float* be_hrz = (const float*)d_in[8];
    const float* w_pk   = (const float*)d_in[9];
    const float* b_pk   = (const float*)d_in[10];
    float* ws  = (float*)d_ws;
    float* out = (float*)d_out;

    k_fused1<<<4096 + NCONVBLK + 8, 256, 0, stream>>>(x, w_vrt, b_vrt, w_hrz, b_hrz, w_pk, ws);
    k_main<<<1024, 256, 0, stream>>>(ws, x, g_vrt, be_vrt, g_hrz, be_hrz, b_pk, out);
}

// Round 3
// 147.097 us; speedup vs baseline: 1.0668x; 1.0257x over previous
//
#include <hip/hip_runtime.h>
#include <math.h>

#define BB 8
#define CCH 32
#define HH 128
#define WW 128
#define OUTC 32
#define NPIX (BB*HH*WW)          // 131072
#define HWP 131                   // padded-coord clamp limit
#define NCONVBLK 2048             // conv blocks (64 px each)

// workspace layout (float offsets) — ~10.6 MB
#define WS_XTB   0                                   // bf16 x_t [b][i][j][c], 8.39 MB
#define WS_CONV4 (BB*HH*WW*CCH/2)                    // pre-BN conv, 4 f/px, 2 MB
#define WS_PART  (WS_CONV4 + BB*HH*WW*4)             // 2048*8 f per-block stats partials
#define WS_WKB   (WS_PART + NCONVBLK*8)              // 16384 ushort bf16 W[o][k], k=n*32+c

// k_main LDS tile: rows i0-4..i0+7 (12), cols j0-4..j0+35 (40), 5-group padding
// offset(r,cc,q) = ((r*40+cc)*5 + q)*8 ushorts = r*1600 + cc*40 + q*8
#define TILE_USH (12*40*5*8)                         // 19200 ushorts = 38400 B

typedef __attribute__((ext_vector_type(8))) short short8;
typedef __attribute__((ext_vector_type(4))) float f32x4;

__device__ __forceinline__ unsigned short f2bf(float f) {
    unsigned u = __float_as_uint(f);
    unsigned r = (u + 0x7FFFu + ((u >> 16) & 1u)) >> 16;   // RTNE
    return (unsigned short)r;
}
// hw packed RTNE f32->bf16x2 (same rounding as f2bf); no builtin on gfx950
__device__ __forceinline__ unsigned cvtpk(float lo, float hi) {
    unsigned r;
    asm("v_cvt_pk_bf16_f32 %0, %1, %2" : "=v"(r) : "v"(lo), "v"(hi));
    return r;
}
__device__ __forceinline__ float bflo(unsigned w) { return __uint_as_float(w << 16); }
__device__ __forceinline__ float bfhi(unsigned w) { return __uint_as_float(w & 0xFFFF0000u); }

// ------- K1: fused conv+partials+transpose->bf16 (center row) | wkb ---------
// Conv blocks also emit the bf16 transposed copy of their center row: the
// k==3 vertical tap IS x[b,c,i,j] — staged to LDS packed, stored once.
__global__ __launch_bounds__(256) void k_fused1(const float* __restrict__ x,
        const float* __restrict__ w_vrt, const float* __restrict__ b_vrt,
        const float* __restrict__ w_hrz, const float* __restrict__ b_hrz,
        const float* __restrict__ w_pk, float* __restrict__ ws) {
    __shared__ float red[4][64][4];
    __shared__ unsigned xrowp[16][65];     // packed bf16 pair per (cpair, px)
    int blk = blockIdx.x, t = threadIdx.x;
    if (blk < NCONVBLK) {
        // ---- conv: 64 px of row (b,i), cols j0c..j0c+63, from NCHW x
        int cb = blk;
        int idx0 = cb * 64;
        int b = idx0 >> 14, ij0 = idx0 & 16383, i = ij0 >> 7, j0c = ij0 & 127;
        int px = t & 63;
        int grp = __builtin_amdgcn_readfirstlane(t >> 6);  // wave-uniform ch group
        float v0 = 0.f, v1 = 0.f, h0 = 0.f, h1 = 0.f;
        float cen_prev = 0.f;
        for (int c8 = 0; c8 < 8; c8++) {
            int c = grp * 8 + c8;
            const float* basec = x + ((size_t)(b*CCH + c))*HH*WW;
            #pragma unroll
            for (int k = 0; k < 7; k++) {
                float wv0 = w_vrt[c*7 + k], wv1 = w_vrt[224 + c*7 + k];
                int gr = i + k - 3;
                if (gr >= 0 && gr < HH) {
                    float xv = basec[(size_t)gr*WW + j0c + px];
                    v0 += wv0 * xv; v1 += wv1 * xv;
                    if (k == 3) {                      // center row: stage for transpose
                        if ((c8 & 1) == 0) cen_prev = xv;
                        else xrowp[grp*4 + (c8 >> 1)][px] = cvtpk(cen_prev, xv);
                    }
                }
                float wh0 = w_hrz[c*7 + k], wh1 = w_hrz[224 + c*7 + k];
                int gc = j0c + px + k - 3;
                if (gc >= 0 && gc < WW) {
                    float xh = basec[(size_t)i*WW + gc];
                    h0 += wh0 * xh; h1 += wh1 * xh;
                }
            }
        }
        red[grp][px][0] = v0; red[grp][px][1] = v1;
        red[grp][px][2] = h0; red[grp][px][3] = h1;
        __syncthreads();
        // ---- transposed bf16 store: 1024 dwords, coalesced
        {
            unsigned* xtb4 = (unsigned*)(ws + WS_XTB);   // 1 dword = 2 channels
            int bi = b*HH + i;
            #pragma unroll
            for (int u = 0; u < 4; u++) {
                int e = u*256 + t;
                int ppx = e >> 4, cp = e & 15;
                xtb4[((size_t)bi*WW + j0c + ppx)*16 + cp] = xrowp[cp][ppx];
            }
        }
        if (grp == 0) {
            float fv0 = red[0][px][0]+red[1][px][0]+red[2][px][0]+red[3][px][0] + b_vrt[0];
            float fv1 = red[0][px][1]+red[1][px][1]+red[2][px][1]+red[3][px][1] + b_vrt[1];
            float fh0 = red[0][px][2]+red[1][px][2]+red[2][px][2]+red[3][px][2] + b_hrz[0];
            float fh1 = red[0][px][3]+red[1][px][3]+red[2][px][3]+red[3][px][3] + b_hrz[1];
            float4* conv4 = (float4*)(ws + WS_CONV4);
            conv4[idx0 + px] = make_float4(fv0, fv1, fh0, fh1);
            float stv[8] = {fv0, fv1, fh0, fh1, fv0*fv0, fv1*fv1, fh0*fh0, fh1*fh1};
            #pragma unroll
            for (int u = 0; u < 8; u++) {
                float s = stv[u];
                for (int off = 32; off; off >>= 1) s += __shfl_down(s, off);
                if (px == 0) ws[WS_PART + cb*8 + u] = s;   // deterministic, no atomics
            }
        }
    } else {
        // ---- wkb: bf16 W[o][k], k = n*32+c
        unsigned short* wkb = (unsigned short*)(ws + WS_WKB);
        int e = (blk - NCONVBLK) * 2048 + t;
        for (int u = 0; u < 8; u++, e += 256) {
            int o = e >> 9, n = (e >> 5) & 15, c = e & 31;
            wkb[o*512 + n*32 + c] = f2bf(w_pk[((o*32 + c) << 4) + n]);
        }
    }
}

// ---- general 2-sample path (only needed for n=11, n=15 clip edge cases) ----
__device__ __forceinline__ short8 sample_frag(const unsigned short* tile,
        const float* xc8, const float* gbv, float fi, float fj, int n,
        float prx, float pry, int i0, int j0, int quad) {
    float mx = 0.f, my = 0.f;
    if (n < 4)       mx = -gbv[0];
    else if (n < 8)  my =  gbv[3];
    else if (n < 12) mx =  gbv[1];
    else             my = -gbv[2];
    float px = fi + prx + mx;
    float py = fj + pry + my;
    float qlx = floorf(px), qly = floorf(py);
    int qlxi = min(max((int)qlx, 0), HWP);
    int qlyi = min(max((int)qly, 0), HWP);
    int qrxi = min(max((int)qlx + 1, 0), HWP);
    int qryi = min(max((int)qly + 1, 0), HWP);
    float pxc = fminf(fmaxf(px, 0.f), (float)HWP);
    float pyc = fminf(fmaxf(py, 0.f), (float)HWP);
    float glt = (1.f + ((float)qlxi - pxc)) * (1.f + ((float)qlyi - pyc));
    float grb = (1.f - ((float)qrxi - pxc)) * (1.f - ((float)qryi - pyc));
    float nglt = -glt, ngrb = -grb;
    // edge pad: x_pad[a] = x[clamp(a-2,0,127)]
    int ltr = min(max(qlxi - 2, 0), HH - 1), ltc = min(max(qlyi - 2, 0), WW - 1);
    int rbr = min(max(qrxi - 2, 0), HH - 1), rbc = min(max(qryi - 2, 0), WW - 1);
    int lt_off = (ltr - i0 + 4)*1600 + (ltc - j0 + 4)*40 + quad*8;
    int rb_off = (rbr - i0 + 4)*1600 + (rbc - j0 + 4)*40 + quad*8;
    uint4 lw = *(const uint4*)(tile + lt_off);
    uint4 rw = *(const uint4*)(tile + rb_off);
    float d0 = fmaf(nglt, bflo(lw.x), fmaf(ngrb, bflo(rw.x), xc8[0]));
    float d1 = fmaf(nglt, bfhi(lw.x), fmaf(ngrb, bfhi(rw.x), xc8[1]));
    float d2 = fmaf(nglt, bflo(lw.y), fmaf(ngrb, bflo(rw.y), xc8[2]));
    float d3 = fmaf(nglt, bfhi(lw.y), fmaf(ngrb, bfhi(rw.y), xc8[3]));
    float d4 = fmaf(nglt, bflo(lw.z), fmaf(ngrb, bflo(rw.z), xc8[4]));
    float d5 = fmaf(nglt, bfhi(lw.z), fmaf(ngrb, bfhi(rw.z), xc8[5]));
    float d6 = fmaf(nglt, bflo(lw.w), fmaf(ngrb, bflo(rw.w), xc8[6]));
    float d7 = fmaf(nglt, bfhi(lw.w), fmaf(ngrb, bfhi(rw.w), xc8[7]));
    uint4 bw;
    bw.x = cvtpk(d0, d1); bw.y = cvtpk(d2, d3);
    bw.z = cvtpk(d4, d5); bw.w = cvtpk(d6, d7);
    return *(short8*)&bw;
}

// ---- fast 1-sample path: the grb term is exactly 0 for n notin {11,15} ----
// (one coordinate per ring-group is integral; q_rb - p == 1 on that axis)
__device__ __forceinline__ void frac_setup(float pm, float& ng, int& m) {
    float qf = floorf(pm);
    int qi = min(max((int)qf, 0), HWP);
    float pmc = fminf(fmaxf(pm, 0.f), (float)HWP);
    ng = pmc - (float)qi - 1.f;                 // = -(1 + qi - pmc) = -g_lt
    m = min(max(qi - 2, 0), HH - 1);            // unpadded moving coord
}
__device__ __forceinline__ short8 samp1(const unsigned short* tile,
        const float* xc8, float ng, int off) {
    uint4 lw = *(const uint4*)(tile + off);
    float d0 = fmaf(ng, bflo(lw.x), xc8[0]);
    float d1 = fmaf(ng, bfhi(lw.x), xc8[1]);
    float d2 = fmaf(ng, bflo(lw.y), xc8[2]);
    float d3 = fmaf(ng, bfhi(lw.y), xc8[3]);
    float d4 = fmaf(ng, bflo(lw.z), xc8[4]);
    float d5 = fmaf(ng, bfhi(lw.z), xc8[5]);
    float d6 = fmaf(ng, bflo(lw.w), xc8[6]);
    float d7 = fmaf(ng, bfhi(lw.w), xc8[7]);
    uint4 bw;
    bw.x = cvtpk(d0, d1); bw.y = cvtpk(d2, d3);
    bw.z = cvtpk(d4, d5); bw.w = cvtpk(d6, d7);
    return *(short8*)&bw;
}

// ---------------- K2: bn-reduce + MFMA main (k_prep folded in) --------------
// 1024 blocks x 256 thr. Block = (b, rows i0..i0+3, cols j0..j0+31) = 128 px.
// Wave w (0..3): row ir = i0+w; tile A = cols j0+pl, tile B = cols j0+16+pl.
__global__ __launch_bounds__(256, 4) void k_main(const float* __restrict__ ws,
        const float* __restrict__ x,
        const float* __restrict__ g_vrt, const float* __restrict__ be_vrt,
        const float* __restrict__ g_hrz, const float* __restrict__ be_hrz,
        const float* __restrict__ b_pk, float* __restrict__ out) {
    __shared__ unsigned short tile[TILE_USH];     // 38400 B
    __shared__ float racc[32][8];                 // 1024 B
    __shared__ float bnab_s[8];
    const unsigned short* xtb = (const unsigned short*)(ws + WS_XTB);
    const unsigned short* wkb = (const unsigned short*)(ws + WS_WKB);
    const float* part = ws + WS_PART;
    const float prfx[16] = {-2,-2,-2,-2, -2,-1, 0, 1,  2, 2, 2, 2, -1, 0, 1, 2};
    const float prfy[16] = {-2,-1, 0, 1,  2, 2, 2, 2, -1, 0, 1, 2, -2,-2,-2,-2};
    // integer-axis per-n offset (col for groups 0,2; row for groups 1,3)
    const int ioffs[16]  = {-2,-1, 0, 1, -2,-1, 0, 1, -1, 0, 1, 2, -1, 0, 1, 2};

    int t = threadIdx.x;
    // XCD-aware bijective swizzle (1024 % 8 == 0): one batch image per XCD
    int blk = ((blockIdx.x & 7) << 7) | (blockIdx.x >> 3);
    int b = blk >> 7;
    int i0 = ((blk >> 2) & 31) * 4;
    int j0 = (blk & 3) * 32;

    // ---- coalesced bf16 tile copy (no conversion), 12 rows x 40 cols
    for (int s = t; s < 12*40*4; s += 256) {
        int q = s & 3, cc = (s >> 2) % 40, r = (s >> 2) / 40;
        int gr = min(max(i0 - 4 + r, 0), HH - 1);
        int gc = min(max(j0 - 4 + cc, 0), WW - 1);
        uint4 v = *(const uint4*)(xtb + (((size_t)(b*HH + gr))*WW + gc)*CCH + q*8);
        *(uint4*)(tile + ((r*40 + cc)*5 + q)*8) = v;
    }
    // ---- bn partial reduce stage 1 (identical summation order to old k_prep)
    {
        int s8 = t & 7, chunk = t >> 3;
        float sum = 0.f;
        #pragma unroll 8
        for (int m = 0; m < 64; m++)
            sum += part[(size_t)(chunk*64 + m)*8 + s8];
        racc[chunk][s8] = sum;
    }
    __syncthreads();
    if (t < 8) {
        float tot = 0.f;
        #pragma unroll
        for (int c = 0; c < 32; c++) tot += racc[c][t];
        racc[0][t] = tot;
    }
    __syncthreads();
    if (t < 4) {
        const float cnt = (float)NPIX;
        float mean = racc[0][t] / cnt;
        float var  = racc[0][4 + t] / cnt - mean * mean;
        float gamma = (t < 2) ? g_vrt[t] : g_hrz[t - 2];
        float beta  = (t < 2) ? be_vrt[t] : be_hrz[t - 2];
        float a = gamma * rsqrtf(var + 1e-5f);
        bnab_s[t]     = a;
        bnab_s[4 + t] = beta - mean * a;
    }
    __syncthreads();

    int w = t >> 6, pl = t & 15, quad = (t >> 4) & 3;
    int ir = i0 + w;
    int pjA = j0 + pl, pjB = j0 + 16 + pl;
    int pixA = (b << 14) + ir * WW + pjA;
    int pixB = pixA + 16;
    int q8 = quad * 8;

    // fp32 center channels for both pixels, straight from NCHW x (exact)
    float xcA[8], xcB[8];
    {
        const float* xb = x + (size_t)b * CCH * HH * WW + (size_t)ir * WW;
        #pragma unroll
        for (int k = 0; k < 8; k++) {
            const float* p = xb + (size_t)(q8 + k) * (HH * WW);
            xcA[k] = p[pjA];
            xcB[k] = p[pjB];
        }
    }
    // gates for both pixels
    const float4* conv4 = (const float4*)(ws + WS_CONV4);
    float4 cvA = conv4[pixA], cvB = conv4[pixB];
    float gbvA[4], gbvB[4];
    gbvA[0] = 2.f / (1.f + expf(-(cvA.x * bnab_s[0] + bnab_s[4])));
    gbvA[1] = 2.f / (1.f + expf(-(cvA.y * bnab_s[1] + bnab_s[5])));
    gbvA[2] = 2.f / (1.f + expf(-(cvA.z * bnab_s[2] + bnab_s[6])));
    gbvA[3] = 2.f / (1.f + expf(-(cvA.w * bnab_s[3] + bnab_s[7])));
    gbvB[0] = 2.f / (1.f + expf(-(cvB.x * bnab_s[0] + bnab_s[4])));
    gbvB[1] = 2.f / (1.f + expf(-(cvB.y * bnab_s[1] + bnab_s[5])));
    gbvB[2] = 2.f / (1.f + expf(-(cvB.z * bnab_s[2] + bnab_s[6])));
    gbvB[3] = 2.f / (1.f + expf(-(cvB.w * bnab_s[3] + bnab_s[7])));

    f32x4 accA0 = {0.f,0.f,0.f,0.f}, accA1 = {0.f,0.f,0.f,0.f};
    f32x4 accB0 = {0.f,0.f,0.f,0.f}, accB1 = {0.f,0.f,0.f,0.f};
    float fi = (float)ir + 2.f;
    float fjA = (float)pjA + 2.f, fjB = (float)pjB + 2.f;

    // weight prefetch pipeline (A-frags shared by both pixel tiles)
    short8 a0 = *(const short8*)(wkb + (size_t)pl * 512 + q8);
    short8 a1 = *(const short8*)(wkb + (size_t)(pl + 16) * 512 + q8);

    // per-group fractional-axis state (recomputed at n = 0,4,8,12)
    float ngA_ = 0.f, ngB_ = 0.f;
    int baseA_ = 0, baseB_ = 0;

    #pragma unroll
    for (int n = 0; n < 16; n++) {
        short8 na0 = a0, na1 = a1;
        if (n < 15) {
            na0 = *(const short8*)(wkb + (size_t)pl * 512 + (n+1)*32 + q8);
            na1 = *(const short8*)(wkb + (size_t)(pl + 16) * 512 + (n+1)*32 + q8);
        }
        if ((n & 3) == 0) {            // group boundary: frac coord constant over 4 n's
            int g = n >> 2;
            float pmA, pmB;
            if (g == 0)      { pmA = (fi  - 2.f) - gbvA[0]; pmB = (fi  - 2.f) - gbvB[0]; }
            else if (g == 1) { pmA = (fjA + 2.f) + gbvA[3]; pmB = (fjB + 2.f) + gbvB[3]; }
            else if (g == 2) { pmA = (fi  + 2.f) + gbvA[1]; pmB = (fi  + 2.f) + gbvB[1]; }
            else             { pmA = (fjA - 2.f) - gbvA[2]; pmB = (fjB - 2.f) - gbvB[2]; }
            int mA, mB;
            frac_setup(pmA, ngA_, mA);
            frac_setup(pmB, ngB_, mB);
            if ((g & 1) == 0) {        // moving axis = row
                baseA_ = (mA - i0 + 4)*1600 + q8;
                baseB_ = (mB - i0 + 4)*1600 + q8;
            } else {                   // moving axis = col
                baseA_ = (mA - j0 + 4)*40 + q8;
                baseB_ = (mB - j0 + 4)*40 + q8;
            }
        }
        short8 bfA, bfB;
        if (n == 11 || n == 15) {      // clip-edge cases: grb can be nonzero
            bfA = sample_frag(tile, xcA, gbvA, fi, fjA, n, prfx[n], prfy[n], i0, j0, quad);
            bfB = sample_frag(tile, xcB, gbvB, fi, fjB, n, prfx[n], prfy[n], i0, j0, quad);
        } else {
            int io = ioffs[n];
            int offA, offB;
            if (((n >> 2) & 1) == 0) { // int axis = col
                int cA = min(max(pjA + io, 0), WW - 1);
                int cB = min(max(pjB + io, 0), WW - 1);
                offA = baseA_ + (cA - j0 + 4)*40;
                offB = baseB_ + (cB - j0 + 4)*40;
            } else {                   // int axis = row (shared by A and B)
                int r  = min(max(ir + io, 0), HH - 1);
                int rt = (r - i0 + 4)*1600;
                offA = baseA_ + rt;
                offB = baseB_ + rt;
            }
            bfA = samp1(tile, xcA, ngA_, offA);
            bfB = samp1(tile, xcB, ngB_, offB);
        }
        accA0 = __builtin_amdgcn_mfma_f32_16x16x32_bf16(a0, bfA, accA0, 0, 0, 0);
        accA1 = __builtin_amdgcn_mfma_f32_16x16x32_bf16(a1, bfA, accA1, 0, 0, 0);
        accB0 = __builtin_amdgcn_mfma_f32_16x16x32_bf16(a0, bfB, accB0, 0, 0, 0);
        accB1 = __builtin_amdgcn_mfma_f32_16x16x32_bf16(a1, bfB, accB1, 0, 0, 0);
        a0 = na0; a1 = na1;
    }
    // epilogue: col = pl (pixel), row = quad*4+reg (out channel)
    float* opA = out + (size_t)b * (OUTC*HH*WW) + ir * WW + pjA;
    float* opB = opA + 16;
    #pragma unroll
    for (int r = 0; r < 4; r++) {
        int o = quad*4 + r;
        float bo = b_pk[o], bo16 = b_pk[o + 16];
        opA[(size_t)o * (HH*WW)]        = accA0[r] + bo;
        opA[(size_t)(o + 16) * (HH*WW)] = accA1[r] + bo16;
        opB[(size_t)o * (HH*WW)]        = accB0[r] + bo;
        opB[(size_t)(o + 16) * (HH*WW)] = accB1[r] + bo16;
    }
}

extern "C" void kernel_launch(void* const* d_in, const int* in_sizes, int n_in,
                              void* d_out, int out_size, void* d_ws, size_t ws_size,
                              hipStream_t stream) {
    const float* x      = (const float*)d_in[0];
    const float* w_vrt  = (const float*)d_in[1];
    const float* b_vrt  = (const float*)d_in[2];
    const float* g_vrt  = (const float*)d_in[3];
    const float* be_vrt = (const float*)d_in[4];
    const float* w_hrz  = (const float*)d_in[5];
    const float* b_hrz  = (const float*)d_in[6];
    const float* g_hrz  = (const float*)d_in[7];
    const float* be_hrz = (const float*)d_in[8];
    const float* w_pk   = (const float*)d_in[9];
    const float* b_pk   = (const float*)d_in[10];
    float* ws  = (float*)d_ws;
    float* out = (float*)d_out;

    k_fused1<<<NCONVBLK + 8, 256, 0, stream>>>(x, w_vrt, b_vrt, w_hrz, b_hrz, w_pk, ws);
    k_main<<<1024, 256, 0, stream>>>(ws, x, g_vrt, be_vrt, g_hrz, be_hrz, b_pk, out);
}

// Round 5
// 128.315 us; speedup vs baseline: 1.2230x; 1.1464x over previous
//
#include <hip/hip_runtime.h>
#include <math.h>

#define BB 8
#define CCH 32
#define HH 128
#define WW 128
#define OUTC 32
#define NPIX (BB*HH*WW)          // 131072
#define HWP 131                   // padded-coord clamp limit

// workspace layout (float offsets) — ~10.6 MB
#define WS_XTB   0                                   // bf16 x_t [b][i][j][c], 8.39 MB
#define WS_VO2   2097152                             // float2 v-conv [pix], 1 MB
#define WS_HO2   (WS_VO2 + NPIX*2)                   // float2 h-conv [pix], 1 MB
#define WS_PARTV (WS_HO2 + NPIX*2)                   // 2048*4 v-stat partials
#define WS_PARTH (WS_PARTV + 2048*4)                 // 1024*4 h-stat partials
#define WS_WKB   (WS_PARTH + 1024*4)                 // 16384 ushort bf16 W[o][k]

// k_main LDS tile: rows i0-4..i0+7 (12), cols j0-4..j0+35 (40), 5-group padding
#define TILE_USH (12*40*5*8)                         // 19200 ushorts = 38400 B

typedef __attribute__((ext_vector_type(8))) short short8;
typedef __attribute__((ext_vector_type(4))) float f32x4;

__device__ __forceinline__ unsigned short f2bf(float f) {
    unsigned u = __float_as_uint(f);
    unsigned r = (u + 0x7FFFu + ((u >> 16) & 1u)) >> 16;   // RTNE
    return (unsigned short)r;
}
// hw packed RTNE f32->bf16x2 (same rounding as f2bf); no builtin on gfx950
__device__ __forceinline__ unsigned cvtpk(float lo, float hi) {
    unsigned r;
    asm("v_cvt_pk_bf16_f32 %0, %1, %2" : "=v"(r) : "v"(lo), "v"(hi));
    return r;
}
__device__ __forceinline__ float bflo(unsigned w) { return __uint_as_float(w << 16); }
__device__ __forceinline__ float bfhi(unsigned w) { return __uint_as_float(w & 0xFFFF0000u); }

// ------- K1: strip-conv (V: 8-row strips | H: float2 col-pairs) | wkb -------
// blk <  256 : vertical conv, 8-row strip x 64 cols; also emits bf16 x_t.
// blk < 1280 : horizontal conv, one full row, 2 cols/thread.
// else       : wkb build (8 blocks).
__global__ __launch_bounds__(256) void k_fused1(const float* __restrict__ x,
        const float* __restrict__ w_vrt, const float* __restrict__ b_vrt,
        const float* __restrict__ w_hrz, const float* __restrict__ b_hrz,
        const float* __restrict__ w_pk, float* __restrict__ ws) {
    __shared__ unsigned sbuf[12288];     // 48 KB: V: xp[8][64][16] + red_v; H: red_h
    int blk = blockIdx.x, t = threadIdx.x;
    if (blk < 256) {
        // ================= vertical pass =================
        // blk = (b*16 + istr)*2 + jh
        int jh = blk & 1, istr = (blk >> 1) & 15, b = blk >> 5;
        int i0 = istr * 8;
        int px = t & 63;
        int sub = __builtin_amdgcn_readfirstlane(t >> 6);
        int col = jh * 64 + px;
        unsigned* xp = sbuf;                                   // [8][64][16] dwords
        float* red_v = (float*)(sbuf + 8192);                  // [4][64][8][2]
        float vo[8][2];
        #pragma unroll
        for (int r = 0; r < 8; r++) { vo[r][0] = 0.f; vo[r][1] = 0.f; }
        float prev[8];
        for (int c8 = 0; c8 < 8; c8++) {
            int c = sub * 8 + c8;
            const float* basec = x + ((size_t)(b*CCH + c))*HH*WW;
            float xv[14];
            #pragma unroll
            for (int rr = 0; rr < 14; rr++) {
                int gr = i0 - 3 + rr;                          // uniform branch
                xv[rr] = ((unsigned)gr < (unsigned)HH) ? basec[(size_t)gr*WW + col] : 0.f;
            }
            #pragma unroll
            for (int r = 0; r < 8; r++) {
                #pragma unroll
                for (int k = 0; k < 7; k++) {
                    float wv0 = w_vrt[c*7 + k], wv1 = w_vrt[224 + c*7 + k];
                    vo[r][0] += wv0 * xv[r + k];
                    vo[r][1] += wv1 * xv[r + k];
                }
            }
            // transpose pack: center rows i0..i0+7 (= xv[3..10]) in channel pairs
            if ((c8 & 1) == 0) {
                #pragma unroll
                for (int r = 0; r < 8; r++) prev[r] = xv[3 + r];
            } else {
                #pragma unroll
                for (int r = 0; r < 8; r++)
                    xp[(r*64 + px)*16 + sub*4 + (c8 >> 1)] = cvtpk(prev[r], xv[3 + r]);
            }
        }
        #pragma unroll
        for (int r = 0; r < 8; r++) {
            red_v[((sub*64 + px)*8 + r)*2 + 0] = vo[r][0];
            red_v[((sub*64 + px)*8 + r)*2 + 1] = vo[r][1];
        }
        __syncthreads();
        // finalize: wave g handles rows 2g, 2g+1 (identical order/stats as before)
        float2* vo2 = (float2*)(ws + WS_VO2);
        #pragma unroll
        for (int h2 = 0; h2 < 2; h2++) {
            int r2 = sub * 2 + h2;
            float fv0 = red_v[((0*64 + px)*8 + r2)*2 + 0] + red_v[((1*64 + px)*8 + r2)*2 + 0]
                      + red_v[((2*64 + px)*8 + r2)*2 + 0] + red_v[((3*64 + px)*8 + r2)*2 + 0]
                      + b_vrt[0];
            float fv1 = red_v[((0*64 + px)*8 + r2)*2 + 1] + red_v[((1*64 + px)*8 + r2)*2 + 1]
                      + red_v[((2*64 + px)*8 + r2)*2 + 1] + red_v[((3*64 + px)*8 + r2)*2 + 1]
                      + b_vrt[1];
            int i = i0 + r2;
            vo2[(size_t)(b << 14) + i * WW + col] = make_float2(fv0, fv1);
            int cb = (b*HH + i)*2 + jh;
            float stv[4] = {fv0, fv1, fv0*fv0, fv1*fv1};
            #pragma unroll
            for (int u = 0; u < 4; u++) {
                float s = stv[u];
                for (int off = 32; off; off >>= 1) s += __shfl_down(s, off);
                if (px == 0) ws[WS_PARTV + cb*4 + u] = s;
            }
        }
        // transposed bf16 store, coalesced uint4
        {
            uint4* xtb4 = (uint4*)(ws + WS_XTB);
            const uint4* xp4 = (const uint4*)xp;
            #pragma unroll
            for (int u = 0; u < 8; u++) {
                int e4 = u*256 + t;
                int rr = e4 >> 8, rem = e4 & 255, jj = rem >> 2, c4 = rem & 3;
                xtb4[(size_t)((b*HH + i0 + rr)*WW + jh*64 + jj)*4 + c4]
                    = xp4[(rr*64 + jj)*4 + c4];
            }
        }
    } else if (blk < 1280) {
        // ================= horizontal pass =================
        int e = blk - 256;                  // row id
        int b = e >> 7, i = e & 127;
        int px2 = t & 63;                   // cols 2*px2, 2*px2+1
        int sub = __builtin_amdgcn_readfirstlane(t >> 6);
        float* red_h = (float*)sbuf;        // [4][64][4]
        // clamped window offsets + validity (same for all channels)
        int cc[5]; bool mv[10];
        #pragma unroll
        for (int u = 0; u < 5; u++) {
            int c2 = 2*px2 - 4 + 2*u;
            cc[u] = min(max(c2, 0), WW - 2);
            mv[2*u]   = (unsigned)c2 < (unsigned)WW;
            mv[2*u+1] = (unsigned)(c2 + 1) < (unsigned)WW;
        }
        float h0A = 0.f, h1A = 0.f, h0B = 0.f, h1B = 0.f;
        for (int c8 = 0; c8 < 8; c8++) {
            int c = sub * 8 + c8;
            const float* rowb = x + ((size_t)(b*CCH + c)*HH + i)*WW;
            float lo[10];
            #pragma unroll
            for (int u = 0; u < 5; u++) {
                float2 v = *(const float2*)(rowb + cc[u]);
                lo[2*u]   = mv[2*u]   ? v.x : 0.f;
                lo[2*u+1] = mv[2*u+1] ? v.y : 0.f;
            }
            #pragma unroll
            for (int k = 0; k < 7; k++) {
                float wh0 = w_hrz[c*7 + k], wh1 = w_hrz[224 + c*7 + k];
                h0A += wh0 * lo[k+1]; h1A += wh1 * lo[k+1];
                h0B += wh0 * lo[k+2]; h1B += wh1 * lo[k+2];
            }
        }
        red_h[(sub*64 + px2)*4 + 0] = h0A;
        red_h[(sub*64 + px2)*4 + 1] = h0B;
        red_h[(sub*64 + px2)*4 + 2] = h1A;
        red_h[(sub*64 + px2)*4 + 3] = h1B;
        __syncthreads();
        if (sub == 0) {
            float fh0A = red_h[(0*64+px2)*4+0] + red_h[(1*64+px2)*4+0]
                       + red_h[(2*64+px2)*4+0] + red_h[(3*64+px2)*4+0] + b_hrz[0];
            float fh0B = red_h[(0*64+px2)*4+1] + red_h[(1*64+px2)*4+1]
                       + red_h[(2*64+px2)*4+1] + red_h[(3*64+px2)*4+1] + b_hrz[0];
            float fh1A = red_h[(0*64+px2)*4+2] + red_h[(1*64+px2)*4+2]
                       + red_h[(2*64+px2)*4+2] + red_h[(3*64+px2)*4+2] + b_hrz[1];
            float fh1B = red_h[(0*64+px2)*4+3] + red_h[(1*64+px2)*4+3]
                       + red_h[(2*64+px2)*4+3] + red_h[(3*64+px2)*4+3] + b_hrz[1];
            float2* ho2 = (float2*)(ws + WS_HO2);
            size_t pix = (size_t)(b << 14) + i * WW + 2*px2;
            *(float4*)(ho2 + pix) = make_float4(fh0A, fh1A, fh0B, fh1B);
            // per-row stat partial (pair-sum then 64-lane tree)
            float stv[4] = {fh0A + fh0B, fh1A + fh1B,
                            fh0A*fh0A + fh0B*fh0B, fh1A*fh1A + fh1B*fh1B};
            #pragma unroll
            for (int u = 0; u < 4; u++) {
                float s = stv[u];
                for (int off = 32; off; off >>= 1) s += __shfl_down(s, off);
                if (px2 == 0) ws[WS_PARTH + e*4 + u] = s;
            }
        }
    } else {
        // ---- wkb: bf16 W[o][k], k = n*32+c
        unsigned short* wkb = (unsigned short*)(ws + WS_WKB);
        int e = (blk - 1280) * 2048 + t;
        for (int u = 0; u < 8; u++, e += 256) {
            int o = e >> 9, n = (e >> 5) & 15, c = e & 31;
            wkb[o*512 + n*32 + c] = f2bf(w_pk[((o*32 + c) << 4) + n]);
        }
    }
}

// ---- general 2-sample path (only needed for n=11, n=15 clip edge cases) ----
__device__ __forceinline__ short8 sample_frag(const unsigned short* tile,
        const float* xc8, const float* gbv, float fi, float fj, int n,
        float prx, float pry, int i0, int j0, int quad) {
    float mx = 0.f, my = 0.f;
    if (n < 4)       mx = -gbv[0];
    else if (n < 8)  my =  gbv[3];
    else if (n < 12) mx =  gbv[1];
    else             my = -gbv[2];
    float px = fi + prx + mx;
    float py = fj + pry + my;
    float qlx = floorf(px), qly = floorf(py);
    int qlxi = min(max((int)qlx, 0), HWP);
    int qlyi = min(max((int)qly, 0), HWP);
    int qrxi = min(max((int)qlx + 1, 0), HWP);
    int qryi = min(max((int)qly + 1, 0), HWP);
    float pxc = fminf(fmaxf(px, 0.f), (float)HWP);
    float pyc = fminf(fmaxf(py, 0.f), (float)HWP);
    float glt = (1.f + ((float)qlxi - pxc)) * (1.f + ((float)qlyi - pyc));
    float grb = (1.f - ((float)qrxi - pxc)) * (1.f - ((float)qryi - pyc));
    float nglt = -glt, ngrb = -grb;
    int ltr = min(max(qlxi - 2, 0), HH - 1), ltc = min(max(qlyi - 2, 0), WW - 1);
    int rbr = min(max(qrxi - 2, 0), HH - 1), rbc = min(max(qryi - 2, 0), WW - 1);
    int lt_off = (ltr - i0 + 4)*1600 + (ltc - j0 + 4)*40 + quad*8;
    int rb_off = (rbr - i0 + 4)*1600 + (rbc - j0 + 4)*40 + quad*8;
    uint4 lw = *(const uint4*)(tile + lt_off);
    uint4 rw = *(const uint4*)(tile + rb_off);
    float d0 = fmaf(nglt, bflo(lw.x), fmaf(ngrb, bflo(rw.x), xc8[0]));
    float d1 = fmaf(nglt, bfhi(lw.x), fmaf(ngrb, bfhi(rw.x), xc8[1]));
    float d2 = fmaf(nglt, bflo(lw.y), fmaf(ngrb, bflo(rw.y), xc8[2]));
    float d3 = fmaf(nglt, bfhi(lw.y), fmaf(ngrb, bfhi(rw.y), xc8[3]));
    float d4 = fmaf(nglt, bflo(lw.z), fmaf(ngrb, bflo(rw.z), xc8[4]));
    float d5 = fmaf(nglt, bfhi(lw.z), fmaf(ngrb, bfhi(rw.z), xc8[5]));
    float d6 = fmaf(nglt, bflo(lw.w), fmaf(ngrb, bflo(rw.w), xc8[6]));
    float d7 = fmaf(nglt, bfhi(lw.w), fmaf(ngrb, bfhi(rw.w), xc8[7]));
    uint4 bw;
    bw.x = cvtpk(d0, d1); bw.y = cvtpk(d2, d3);
    bw.z = cvtpk(d4, d5); bw.w = cvtpk(d6, d7);
    return *(short8*)&bw;
}

// ---- fast 1-sample path: the grb term is exactly 0 for n notin {11,15} ----
__device__ __forceinline__ void frac_setup(float pm, float& ng, int& m) {
    float qf = floorf(pm);
    int qi = min(max((int)qf, 0), HWP);
    float pmc = fminf(fmaxf(pm, 0.f), (float)HWP);
    ng = pmc - (float)qi - 1.f;                 // = -(1 + qi - pmc) = -g_lt
    m = min(max(qi - 2, 0), HH - 1);            // unpadded moving coord
}
__device__ __forceinline__ short8 samp1(const unsigned short* tile,
        const float* xc8, float ng, int off) {
    uint4 lw = *(const uint4*)(tile + off);
    float d0 = fmaf(ng, bflo(lw.x), xc8[0]);
    float d1 = fmaf(ng, bfhi(lw.x), xc8[1]);
    float d2 = fmaf(ng, bflo(lw.y), xc8[2]);
    float d3 = fmaf(ng, bfhi(lw.y), xc8[3]);
    float d4 = fmaf(ng, bflo(lw.z), xc8[4]);
    float d5 = fmaf(ng, bfhi(lw.z), xc8[5]);
    float d6 = fmaf(ng, bflo(lw.w), xc8[6]);
    float d7 = fmaf(ng, bfhi(lw.w), xc8[7]);
    uint4 bw;
    bw.x = cvtpk(d0, d1); bw.y = cvtpk(d2, d3);
    bw.z = cvtpk(d4, d5); bw.w = cvtpk(d6, d7);
    return *(short8*)&bw;
}

// ---------------- K2: bn-reduce + MFMA main ---------------------------------
__global__ __launch_bounds__(256, 4) void k_main(const float* __restrict__ ws,
        const float* __restrict__ x,
        const float* __restrict__ g_vrt, const float* __restrict__ be_vrt,
        const float* __restrict__ g_hrz, const float* __restrict__ be_hrz,
        const float* __restrict__ b_pk, float* __restrict__ out) {
    __shared__ unsigned short tile[TILE_USH];     // 38400 B
    __shared__ float racc[32][8];                 // 1024 B
    __shared__ float bnab_s[8];
    const unsigned short* xtb = (const unsigned short*)(ws + WS_XTB);
    const unsigned short* wkb = (const unsigned short*)(ws + WS_WKB);
    const float* partv = ws + WS_PARTV;
    const float* parth = ws + WS_PARTH;
    const float prfx[16] = {-2,-2,-2,-2, -2,-1, 0, 1,  2, 2, 2, 2, -1, 0, 1, 2};
    const float prfy[16] = {-2,-1, 0, 1,  2, 2, 2, 2, -1, 0, 1, 2, -2,-2,-2,-2};
    const int ioffs[16]  = {-2,-1, 0, 1, -2,-1, 0, 1, -1, 0, 1, 2, -1, 0, 1, 2};

    int t = threadIdx.x;
    // XCD-aware bijective swizzle (1024 % 8 == 0)
    int blk = ((blockIdx.x & 7) << 7) | (blockIdx.x >> 3);
    int b = blk >> 7;
    int i0 = ((blk >> 2) & 31) * 4;
    int j0 = (blk & 3) * 32;

    // ---- coalesced bf16 tile copy, 12 rows x 40 cols
    for (int s = t; s < 12*40*4; s += 256) {
        int q = s & 3, cc = (s >> 2) % 40, r = (s >> 2) / 40;
        int gr = min(max(i0 - 4 + r, 0), HH - 1);
        int gc = min(max(j0 - 4 + cc, 0), WW - 1);
        uint4 v = *(const uint4*)(xtb + (((size_t)(b*HH + gr))*WW + gc)*CCH + q*8);
        *(uint4*)(tile + ((r*40 + cc)*5 + q)*8) = v;
    }
    // ---- bn partial reduce stage 1 (v: 2048 cbs, h: 1024 cbs)
    {
        int s8 = t & 7, chunk = t >> 3;
        int col = (s8 & 1) + ((s8 >> 2) << 1);
        bool isv = ((s8 >> 1) & 1) == 0;
        float sum = 0.f;
        if (isv) {
            for (int m = 0; m < 64; m++)
                sum += partv[(size_t)(chunk*64 + m)*4 + col];
        } else {
            for (int m = 0; m < 32; m++)
                sum += parth[(size_t)(chunk*32 + m)*4 + col];
        }
        racc[chunk][s8] = sum;
    }
    __syncthreads();
    if (t < 8) {
        float tot = 0.f;
        #pragma unroll
        for (int c = 0; c < 32; c++) tot += racc[c][t];
        racc[0][t] = tot;
    }
    __syncthreads();
    if (t < 4) {
        const float cnt = (float)NPIX;
        float mean = racc[0][t] / cnt;
        float var  = racc[0][4 + t] / cnt - mean * mean;
        float gamma = (t < 2) ? g_vrt[t] : g_hrz[t - 2];
        float beta  = (t < 2) ? be_vrt[t] : be_hrz[t - 2];
        float a = gamma * rsqrtf(var + 1e-5f);
        bnab_s[t]     = a;
        bnab_s[4 + t] = beta - mean * a;
    }
    __syncthreads();

    int w = t >> 6, pl = t & 15, quad = (t >> 4) & 3;
    int ir = i0 + w;
    int pjA = j0 + pl, pjB = j0 + 16 + pl;
    int pixA = (b << 14) + ir * WW + pjA;
    int pixB = pixA + 16;
    int q8 = quad * 8;

    // fp32 center channels for both pixels, straight from NCHW x (exact)
    float xcA[8], xcB[8];
    {
        const float* xb = x + (size_t)b * CCH * HH * WW + (size_t)ir * WW;
        #pragma unroll
        for (int k = 0; k < 8; k++) {
            const float* p = xb + (size_t)(q8 + k) * (HH * WW);
            xcA[k] = p[pjA];
            xcB[k] = p[pjB];
        }
    }
    // gates for both pixels
    const float2* vo2 = (const float2*)(ws + WS_VO2);
    const float2* ho2 = (const float2*)(ws + WS_HO2);
    float2 vA = vo2[pixA], hA = ho2[pixA];
    float2 vB = vo2[pixB], hB = ho2[pixB];
    float gbvA[4], gbvB[4];
    gbvA[0] = 2.f / (1.f + expf(-(vA.x * bnab_s[0] + bnab_s[4])));
    gbvA[1] = 2.f / (1.f + expf(-(vA.y * bnab_s[1] + bnab_s[5])));
    gbvA[2] = 2.f / (1.f + expf(-(hA.x * bnab_s[2] + bnab_s[6])));
    gbvA[3] = 2.f / (1.f + expf(-(hA.y * bnab_s[3] + bnab_s[7])));
    gbvB[0] = 2.f / (1.f + expf(-(vB.x * bnab_s[0] + bnab_s[4])));
    gbvB[1] = 2.f / (1.f + expf(-(vB.y * bnab_s[1] + bnab_s[5])));
    gbvB[2] = 2.f / (1.f + expf(-(hB.x * bnab_s[2] + bnab_s[6])));
    gbvB[3] = 2.f / (1.f + expf(-(hB.y * bnab_s[3] + bnab_s[7])));

    f32x4 accA0 = {0.f,0.f,0.f,0.f}, accA1 = {0.f,0.f,0.f,0.f};
    f32x4 accB0 = {0.f,0.f,0.f,0.f}, accB1 = {0.f,0.f,0.f,0.f};
    float fi = (float)ir + 2.f;
    float fjA = (float)pjA + 2.f, fjB = (float)pjB + 2.f;

    short8 a0 = *(const short8*)(wkb + (size_t)pl * 512 + q8);
    short8 a1 = *(const short8*)(wkb + (size_t)(pl + 16) * 512 + q8);

    float ngA_ = 0.f, ngB_ = 0.f;
    int baseA_ = 0, baseB_ = 0;

    #pragma unroll
    for (int n = 0; n < 16; n++) {
        short8 na0 = a0, na1 = a1;
        if (n < 15) {
            na0 = *(const short8*)(wkb + (size_t)pl * 512 + (n+1)*32 + q8);
            na1 = *(const short8*)(wkb + (size_t)(pl + 16) * 512 + (n+1)*32 + q8);
        }
        if ((n & 3) == 0) {            // group boundary: frac coord constant over 4 n's
            int g = n >> 2;
            float pmA, pmB;
            if (g == 0)      { pmA = (fi  - 2.f) - gbvA[0]; pmB = (fi  - 2.f) - gbvB[0]; }
            else if (g == 1) { pmA = (fjA + 2.f) + gbvA[3]; pmB = (fjB + 2.f) + gbvB[3]; }
            else if (g == 2) { pmA = (fi  + 2.f) + gbvA[1]; pmB = (fi  + 2.f) + gbvB[1]; }
            else             { pmA = (fjA - 2.f) - gbvA[2]; pmB = (fjB - 2.f) - gbvB[2]; }
            int mA, mB;
            frac_setup(pmA, ngA_, mA);
            frac_setup(pmB, ngB_, mB);
            if ((g & 1) == 0) {        // moving axis = row
                baseA_ = (mA - i0 + 4)*1600 + q8;
                baseB_ = (mB - i0 + 4)*1600 + q8;
            } else {                   // moving axis = col
                baseA_ = (mA - j0 + 4)*40 + q8;
                baseB_ = (mB - j0 + 4)*40 + q8;
            }
        }
        short8 bfA, bfB;
        if (n == 11 || n == 15) {      // clip-edge cases: grb can be nonzero
            bfA = sample_frag(tile, xcA, gbvA, fi, fjA, n, prfx[n], prfy[n], i0, j0, quad);
            bfB = sample_frag(tile, xcB, gbvB, fi, fjB, n, prfx[n], prfy[n], i0, j0, quad);
        } else {
            int io = ioffs[n];
            int offA, offB;
            if (((n >> 2) & 1) == 0) { // int axis = col
                int cA = min(max(pjA + io, 0), WW - 1);
                int cB = min(max(pjB + io, 0), WW - 1);
                offA = baseA_ + (cA - j0 + 4)*40;
                offB = baseB_ + (cB - j0 + 4)*40;
            } else {                   // int axis = row (shared by A and B)
                int r  = min(max(ir + io, 0), HH - 1);
                int rt = (r - i0 + 4)*1600;
                offA = baseA_ + rt;
                offB = baseB_ + rt;
            }
            bfA = samp1(tile, xcA, ngA_, offA);
            bfB = samp1(tile, xcB, ngB_, offB);
        }
        accA0 = __builtin_amdgcn_mfma_f32_16x16x32_bf16(a0, bfA, accA0, 0, 0, 0);
        accA1 = __builtin_amdgcn_mfma_f32_16x16x32_bf16(a1, bfA, accA1, 0, 0, 0);
        accB0 = __builtin_amdgcn_mfma_f32_16x16x32_bf16(a0, bfB, accB0, 0, 0, 0);
        accB1 = __builtin_amdgcn_mfma_f32_16x16x32_bf16(a1, bfB, accB1, 0, 0, 0);
        a0 = na0; a1 = na1;
    }
    // epilogue
    float* opA = out + (size_t)b * (OUTC*HH*WW) + ir * WW + pjA;
    float* opB = opA + 16;
    #pragma unroll
    for (int r = 0; r < 4; r++) {
        int o = quad*4 + r;
        float bo = b_pk[o], bo16 = b_pk[o + 16];
        opA[(size_t)o * (HH*WW)]        = accA0[r] + bo;
        opA[(size_t)(o + 16) * (HH*WW)] = accA1[r] + bo16;
        opB[(size_t)o * (HH*WW)]        = accB0[r] + bo;
        opB[(size_t)(o + 16) * (HH*WW)] = accB1[r] + bo16;
    }
}

extern "C" void kernel_launch(void* const* d_in, const int* in_sizes, int n_in,
                              void* d_out, int out_size, void* d_ws, size_t ws_size,
                              hipStream_t stream) {
    const float* x      = (const float*)d_in[0];
    const float* w_vrt  = (const float*)d_in[1];
    const float* b_vrt  = (const float*)d_in[2];
    const float* g_vrt  = (const float*)d_in[3];
    const float* be_vrt = (const float*)d_in[4];
    const float* w_hrz  = (const float*)d_in[5];
    const float* b_hrz  = (const float*)d_in[6];
    const float* g_hrz  = (const float*)d_in[7];
    const float* be_hrz = (const float*)d_in[8];
    const float* w_pk   = (const float*)d_in[9];
    const float* b_pk   = (const float*)d_in[10];
    float* ws  = (float*)d_ws;
    float* out = (float*)d_out;

    k_fused1<<<256 + 1024 + 8, 256, 0, stream>>>(x, w_vrt, b_vrt, w_hrz, b_hrz, w_pk, ws);
    k_main<<<1024, 256, 0, stream>>>(ws, x, g_vrt, be_vrt, g_hrz, be_hrz, b_pk, out);
}

// Round 6
// 123.870 us; speedup vs baseline: 1.2669x; 1.0359x over previous
//
#include <hip/hip_runtime.h>
#include <math.h>

#define BB 8
#define CCH 32
#define HH 128
#define WW 128
#define OUTC 32
#define NPIX (BB*HH*WW)          // 131072
#define HWP 131                   // padded-coord clamp limit

// workspace layout (float offsets) — ~10.7 MB
#define WS_XTB   0                                   // bf16 x_t [b][i][j][c], 8.39 MB
#define WS_VO2   2097152                             // float2 v-conv [pix], 1 MB
#define WS_HO2   (WS_VO2 + NPIX*2)                   // float2 h-conv [pix], 1 MB
#define WS_PARTV (WS_HO2 + NPIX*2)                   // 4096*4 v-stat partials
#define WS_PARTH (WS_PARTV + 4096*4)                 // 1024*4 h-stat partials
#define WS_WKB   (WS_PARTH + 1024*4)                 // 16384 ushort bf16 W[o][k]

// k_main LDS tile: rows i0-4..i0+7 (12), cols j0-4..j0+35 (40), 5-group padding
#define TILE_USH (12*40*5*8)                         // 19200 ushorts = 38400 B

typedef __attribute__((ext_vector_type(8))) short short8;
typedef __attribute__((ext_vector_type(4))) float f32x4;

__device__ __forceinline__ unsigned short f2bf(float f) {
    unsigned u = __float_as_uint(f);
    unsigned r = (u + 0x7FFFu + ((u >> 16) & 1u)) >> 16;   // RTNE
    return (unsigned short)r;
}
// hw packed RTNE f32->bf16x2 (same rounding as f2bf); no builtin on gfx950
__device__ __forceinline__ unsigned cvtpk(float lo, float hi) {
    unsigned r;
    asm("v_cvt_pk_bf16_f32 %0, %1, %2" : "=v"(r) : "v"(lo), "v"(hi));
    return r;
}
__device__ __forceinline__ float bflo(unsigned w) { return __uint_as_float(w << 16); }
__device__ __forceinline__ float bfhi(unsigned w) { return __uint_as_float(w & 0xFFFF0000u); }

// ------- K1: strip-conv (V: 8x32 strips | H: float2 col-pairs) | wkb --------
// blk <  512 : vertical conv, 8-row x 32-col strip; also emits bf16 x_t.
// blk < 1536 : horizontal conv, one full row, 2 cols/thread.
// else       : wkb build (8 blocks).
__global__ __launch_bounds__(256) void k_fused1(const float* __restrict__ x,
        const float* __restrict__ w_vrt, const float* __restrict__ b_vrt,
        const float* __restrict__ w_hrz, const float* __restrict__ b_hrz,
        const float* __restrict__ w_pk, float* __restrict__ ws) {
    __shared__ unsigned sbuf[8448];      // 33 KB: V: xp[4096] + red_v[4352]; H: red_h
    int blk = blockIdx.x, t = threadIdx.x;
    if (blk < 512) {
        // ================= vertical pass =================
        // blk = ((b*16 + istr) << 2) | jq
        int jq = blk & 3, istr = (blk >> 2) & 15, b = blk >> 6;
        int i0 = istr * 8;
        int px = t & 31;
        int sub = t >> 5;                              // 8 groups of 4 channels
        int col = jq * 32 + px;
        unsigned* xp = sbuf;                           // [8 r][32 px][16 cp] dwords
        float* red_v = (float*)(sbuf + 4096);          // [(sub*32+px)*17 + r*2+o]
        float vo[8][2];
        #pragma unroll
        for (int r = 0; r < 8; r++) { vo[r][0] = 0.f; vo[r][1] = 0.f; }
        float prev[8];
        for (int c4 = 0; c4 < 4; c4++) {
            int c = sub * 4 + c4;
            const float* basec = x + ((size_t)(b*CCH + c))*HH*WW;
            float xv[14];
            #pragma unroll
            for (int rr = 0; rr < 14; rr++) {
                int gr = i0 - 3 + rr;
                xv[rr] = ((unsigned)gr < (unsigned)HH) ? basec[(size_t)gr*WW + col] : 0.f;
            }
            #pragma unroll
            for (int r = 0; r < 8; r++) {
                #pragma unroll
                for (int k = 0; k < 7; k++) {
                    float wv0 = w_vrt[c*7 + k], wv1 = w_vrt[224 + c*7 + k];
                    vo[r][0] += wv0 * xv[r + k];
                    vo[r][1] += wv1 * xv[r + k];
                }
            }
            // transpose pack: center rows i0..i0+7 (= xv[3..10]) in channel pairs
            if ((c4 & 1) == 0) {
                #pragma unroll
                for (int r = 0; r < 8; r++) prev[r] = xv[3 + r];
            } else {
                #pragma unroll
                for (int r = 0; r < 8; r++)
                    xp[(r*32 + px)*16 + sub*2 + (c4 >> 1)] = cvtpk(prev[r], xv[3 + r]);
            }
        }
        #pragma unroll
        for (int r = 0; r < 8; r++) {
            red_v[(sub*32 + px)*17 + r*2 + 0] = vo[r][0];
            red_v[(sub*32 + px)*17 + r*2 + 1] = vo[r][1];
        }
        __syncthreads();
        // combine: thread t -> (row rr = t>>5, col pxc = t&31); sum 8 sub-groups
        {
            int rr = t >> 5, pxc = t & 31;
            float s0 = red_v[(0*32 + pxc)*17 + rr*2 + 0];
            float s1 = red_v[(0*32 + pxc)*17 + rr*2 + 1];
            #pragma unroll
            for (int sb = 1; sb < 8; sb++) {
                s0 += red_v[(sb*32 + pxc)*17 + rr*2 + 0];
                s1 += red_v[(sb*32 + pxc)*17 + rr*2 + 1];
            }
            float fv0 = s0 + b_vrt[0], fv1 = s1 + b_vrt[1];
            int i = i0 + rr;
            float2* vo2 = (float2*)(ws + WS_VO2);
            vo2[(size_t)(b << 14) + i * WW + jq*32 + pxc] = make_float2(fv0, fv1);
            int cb4 = (b*HH + i)*4 + jq;
            float stv[4] = {fv0, fv1, fv0*fv0, fv1*fv1};
            #pragma unroll
            for (int u = 0; u < 4; u++) {
                float s = stv[u];
                for (int off = 16; off; off >>= 1) s += __shfl_down(s, off);
                if (pxc == 0) ws[WS_PARTV + cb4*4 + u] = s;
            }
        }
        // transposed bf16 store, coalesced uint4 (1024 uint4)
        {
            uint4* xtb4 = (uint4*)(ws + WS_XTB);
            const uint4* xp4 = (const uint4*)xp;
            #pragma unroll
            for (int u = 0; u < 4; u++) {
                int e4 = u*256 + t;
                int rr2 = e4 >> 7, rem = e4 & 127, jj = rem >> 2, c4i = rem & 3;
                xtb4[(size_t)((b*HH + i0 + rr2)*WW + jq*32 + jj)*4 + c4i] = xp4[e4];
            }
        }
    } else if (blk < 1536) {
        // ================= horizontal pass =================
        int e = blk - 512;                  // row id
        int b = e >> 7, i = e & 127;
        int px2 = t & 63;                   // cols 2*px2, 2*px2+1
        int sub = __builtin_amdgcn_readfirstlane(t >> 6);
        float* red_h = (float*)sbuf;        // [4][64][4]
        int cc[5]; bool mv[10];
        #pragma unroll
        for (int u = 0; u < 5; u++) {
            int c2 = 2*px2 - 4 + 2*u;
            cc[u] = min(max(c2, 0), WW - 2);
            mv[2*u]   = (unsigned)c2 < (unsigned)WW;
            mv[2*u+1] = (unsigned)(c2 + 1) < (unsigned)WW;
        }
        float h0A = 0.f, h1A = 0.f, h0B = 0.f, h1B = 0.f;
        for (int c8 = 0; c8 < 8; c8++) {
            int c = sub * 8 + c8;
            const float* rowb = x + ((size_t)(b*CCH + c)*HH + i)*WW;
            float lo[10];
            #pragma unroll
            for (int u = 0; u < 5; u++) {
                float2 v = *(const float2*)(rowb + cc[u]);
                lo[2*u]   = mv[2*u]   ? v.x : 0.f;
                lo[2*u+1] = mv[2*u+1] ? v.y : 0.f;
            }
            #pragma unroll
            for (int k = 0; k < 7; k++) {
                float wh0 = w_hrz[c*7 + k], wh1 = w_hrz[224 + c*7 + k];
                h0A += wh0 * lo[k+1]; h1A += wh1 * lo[k+1];
                h0B += wh0 * lo[k+2]; h1B += wh1 * lo[k+2];
            }
        }
        red_h[(sub*64 + px2)*4 + 0] = h0A;
        red_h[(sub*64 + px2)*4 + 1] = h0B;
        red_h[(sub*64 + px2)*4 + 2] = h1A;
        red_h[(sub*64 + px2)*4 + 3] = h1B;
        __syncthreads();
        if (sub == 0) {
            float fh0A = red_h[(0*64+px2)*4+0] + red_h[(1*64+px2)*4+0]
                       + red_h[(2*64+px2)*4+0] + red_h[(3*64+px2)*4+0] + b_hrz[0];
            float fh0B = red_h[(0*64+px2)*4+1] + red_h[(1*64+px2)*4+1]
                       + red_h[(2*64+px2)*4+1] + red_h[(3*64+px2)*4+1] + b_hrz[0];
            float fh1A = red_h[(0*64+px2)*4+2] + red_h[(1*64+px2)*4+2]
                       + red_h[(2*64+px2)*4+2] + red_h[(3*64+px2)*4+2] + b_hrz[1];
            float fh1B = red_h[(0*64+px2)*4+3] + red_h[(1*64+px2)*4+3]
                       + red_h[(2*64+px2)*4+3] + red_h[(3*64+px2)*4+3] + b_hrz[1];
            float2* ho2 = (float2*)(ws + WS_HO2);
            size_t pix = (size_t)(b << 14) + i * WW + 2*px2;
            *(float4*)(ho2 + pix) = make_float4(fh0A, fh1A, fh0B, fh1B);
            float stv[4] = {fh0A + fh0B, fh1A + fh1B,
                            fh0A*fh0A + fh0B*fh0B, fh1A*fh1A + fh1B*fh1B};
            #pragma unroll
            for (int u = 0; u < 4; u++) {
                float s = stv[u];
                for (int off = 32; off; off >>= 1) s += __shfl_down(s, off);
                if (px2 == 0) ws[WS_PARTH + e*4 + u] = s;
            }
        }
    } else {
        // ---- wkb: bf16 W[o][k], k = n*32+c
        unsigned short* wkb = (unsigned short*)(ws + WS_WKB);
        int e = (blk - 1536) * 2048 + t;
        for (int u = 0; u < 8; u++, e += 256) {
            int o = e >> 9, n = (e >> 5) & 15, c = e & 31;
            wkb[o*512 + n*32 + c] = f2bf(w_pk[((o*32 + c) << 4) + n]);
        }
    }
}

// ---- general 2-sample path (only needed for n=11, n=15 clip edge cases) ----
__device__ __forceinline__ short8 sample_frag(const unsigned short* tile,
        const float* xc8, const float* gbv, float fi, float fj, int n,
        float prx, float pry, int i0, int j0, int quad) {
    float mx = 0.f, my = 0.f;
    if (n < 4)       mx = -gbv[0];
    else if (n < 8)  my =  gbv[3];
    else if (n < 12) mx =  gbv[1];
    else             my = -gbv[2];
    float px = fi + prx + mx;
    float py = fj + pry + my;
    float qlx = floorf(px), qly = floorf(py);
    int qlxi = min(max((int)qlx, 0), HWP);
    int qlyi = min(max((int)qly, 0), HWP);
    int qrxi = min(max((int)qlx + 1, 0), HWP);
    int qryi = min(max((int)qly + 1, 0), HWP);
    float pxc = fminf(fmaxf(px, 0.f), (float)HWP);
    float pyc = fminf(fmaxf(py, 0.f), (float)HWP);
    float glt = (1.f + ((float)qlxi - pxc)) * (1.f + ((float)qlyi - pyc));
    float grb = (1.f - ((float)qrxi - pxc)) * (1.f - ((float)qryi - pyc));
    float nglt = -glt, ngrb = -grb;
    int ltr = min(max(qlxi - 2, 0), HH - 1), ltc = min(max(qlyi - 2, 0), WW - 1);
    int rbr = min(max(qrxi - 2, 0), HH - 1), rbc = min(max(qryi - 2, 0), WW - 1);
    int lt_off = (ltr - i0 + 4)*1600 + (ltc - j0 + 4)*40 + quad*8;
    int rb_off = (rbr - i0 + 4)*1600 + (rbc - j0 + 4)*40 + quad*8;
    uint4 lw = *(const uint4*)(tile + lt_off);
    uint4 rw = *(const uint4*)(tile + rb_off);
    float d0 = fmaf(nglt, bflo(lw.x), fmaf(ngrb, bflo(rw.x), xc8[0]));
    float d1 = fmaf(nglt, bfhi(lw.x), fmaf(ngrb, bfhi(rw.x), xc8[1]));
    float d2 = fmaf(nglt, bflo(lw.y), fmaf(ngrb, bflo(rw.y), xc8[2]));
    float d3 = fmaf(nglt, bfhi(lw.y), fmaf(ngrb, bfhi(rw.y), xc8[3]));
    float d4 = fmaf(nglt, bflo(lw.z), fmaf(ngrb, bflo(rw.z), xc8[4]));
    float d5 = fmaf(nglt, bfhi(lw.z), fmaf(ngrb, bfhi(rw.z), xc8[5]));
    float d6 = fmaf(nglt, bflo(lw.w), fmaf(ngrb, bflo(rw.w), xc8[6]));
    float d7 = fmaf(nglt, bfhi(lw.w), fmaf(ngrb, bfhi(rw.w), xc8[7]));
    uint4 bw;
    bw.x = cvtpk(d0, d1); bw.y = cvtpk(d2, d3);
    bw.z = cvtpk(d4, d5); bw.w = cvtpk(d6, d7);
    return *(short8*)&bw;
}

// ---- fast 1-sample path: the grb term is exactly 0 for n notin {11,15} ----
__device__ __forceinline__ void frac_setup(float pm, float& ng, int& m) {
    float qf = floorf(pm);
    int qi = min(max((int)qf, 0), HWP);
    float pmc = fminf(fmaxf(pm, 0.f), (float)HWP);
    ng = pmc - (float)qi - 1.f;                 // = -(1 + qi - pmc) = -g_lt
    m = min(max(qi - 2, 0), HH - 1);            // unpadded moving coord
}
__device__ __forceinline__ short8 samp1(const unsigned short* tile,
        const float* xc8, float ng, int off) {
    uint4 lw = *(const uint4*)(tile + off);
    float d0 = fmaf(ng, bflo(lw.x), xc8[0]);
    float d1 = fmaf(ng, bfhi(lw.x), xc8[1]);
    float d2 = fmaf(ng, bflo(lw.y), xc8[2]);
    float d3 = fmaf(ng, bfhi(lw.y), xc8[3]);
    float d4 = fmaf(ng, bflo(lw.z), xc8[4]);
    float d5 = fmaf(ng, bfhi(lw.z), xc8[5]);
    float d6 = fmaf(ng, bflo(lw.w), xc8[6]);
    float d7 = fmaf(ng, bfhi(lw.w), xc8[7]);
    uint4 bw;
    bw.x = cvtpk(d0, d1); bw.y = cvtpk(d2, d3);
    bw.z = cvtpk(d4, d5); bw.w = cvtpk(d6, d7);
    return *(short8*)&bw;
}

// ---------------- K2: bn-reduce + MFMA main ---------------------------------
__global__ __launch_bounds__(256, 4) void k_main(const float* __restrict__ ws,
        const float* __restrict__ x,
        const float* __restrict__ g_vrt, const float* __restrict__ be_vrt,
        const float* __restrict__ g_hrz, const float* __restrict__ be_hrz,
        const float* __restrict__ b_pk, float* __restrict__ out) {
    __shared__ unsigned short tile[TILE_USH];     // 38400 B
    __shared__ float racc[4][8];                  // 128 B
    __shared__ float bnab_s[8];
    const unsigned short* xtb = (const unsigned short*)(ws + WS_XTB);
    const unsigned short* wkb = (const unsigned short*)(ws + WS_WKB);
    const float prfx[16] = {-2,-2,-2,-2, -2,-1, 0, 1,  2, 2, 2, 2, -1, 0, 1, 2};
    const float prfy[16] = {-2,-1, 0, 1,  2, 2, 2, 2, -1, 0, 1, 2, -2,-2,-2,-2};
    const int ioffs[16]  = {-2,-1, 0, 1, -2,-1, 0, 1, -1, 0, 1, 2, -1, 0, 1, 2};

    int t = threadIdx.x;
    // XCD-aware bijective swizzle (1024 % 8 == 0)
    int blk = ((blockIdx.x & 7) << 7) | (blockIdx.x >> 3);
    int b = blk >> 7;
    int i0 = ((blk >> 2) & 31) * 4;
    int j0 = (blk & 3) * 32;

    // ---- coalesced bf16 tile copy, 12 rows x 40 cols
    for (int s = t; s < 12*40*4; s += 256) {
        int q = s & 3, cc = (s >> 2) % 40, r = (s >> 2) / 40;
        int gr = min(max(i0 - 4 + r, 0), HH - 1);
        int gc = min(max(j0 - 4 + cc, 0), WW - 1);
        uint4 v = *(const uint4*)(xtb + (((size_t)(b*HH + gr))*WW + gc)*CCH + q*8);
        *(uint4*)(tile + ((r*40 + cc)*5 + q)*8) = v;
    }
    // ---- bn partial reduce: coalesced float4 + wave shuffle tree
    {
        const float4* pv4 = (const float4*)(ws + WS_PARTV);   // 4096 entries
        const float4* ph4 = (const float4*)(ws + WS_PARTH);   // 1024 entries
        float4 sv = make_float4(0.f,0.f,0.f,0.f), sh = make_float4(0.f,0.f,0.f,0.f);
        #pragma unroll 4
        for (int m = 0; m < 16; m++) {
            float4 v = pv4[t + 256*m];
            sv.x += v.x; sv.y += v.y; sv.z += v.z; sv.w += v.w;
        }
        #pragma unroll 4
        for (int m = 0; m < 4; m++) {
            float4 v = ph4[t + 256*m];
            sh.x += v.x; sh.y += v.y; sh.z += v.z; sh.w += v.w;
        }
        #pragma unroll
        for (int off = 32; off; off >>= 1) {
            sv.x += __shfl_down(sv.x, off); sv.y += __shfl_down(sv.y, off);
            sv.z += __shfl_down(sv.z, off); sv.w += __shfl_down(sv.w, off);
            sh.x += __shfl_down(sh.x, off); sh.y += __shfl_down(sh.y, off);
            sh.z += __shfl_down(sh.z, off); sh.w += __shfl_down(sh.w, off);
        }
        if ((t & 63) == 0) {
            int wv = t >> 6;
            racc[wv][0] = sv.x; racc[wv][1] = sv.y; racc[wv][2] = sh.x; racc[wv][3] = sh.y;
            racc[wv][4] = sv.z; racc[wv][5] = sv.w; racc[wv][6] = sh.z; racc[wv][7] = sh.w;
        }
    }
    __syncthreads();
    if (t < 8)
        racc[0][t] = racc[0][t] + racc[1][t] + racc[2][t] + racc[3][t];
    __syncthreads();
    if (t < 4) {
        const float cnt = (float)NPIX;
        float mean = racc[0][t] / cnt;
        float var  = racc[0][4 + t] / cnt - mean * mean;
        float gamma = (t < 2) ? g_vrt[t] : g_hrz[t - 2];
        float beta  = (t < 2) ? be_vrt[t] : be_hrz[t - 2];
        float a = gamma * rsqrtf(var + 1e-5f);
        bnab_s[t]     = a;
        bnab_s[4 + t] = beta - mean * a;
    }
    __syncthreads();

    int w = t >> 6, pl = t & 15, quad = (t >> 4) & 3;
    int ir = i0 + w;
    int pjA = j0 + pl, pjB = j0 + 16 + pl;
    int pixA = (b << 14) + ir * WW + pjA;
    int pixB = pixA + 16;
    int q8 = quad * 8;

    // fp32 center channels for both pixels, straight from NCHW x (exact)
    float xcA[8], xcB[8];
    {
        const float* xb = x + (size_t)b * CCH * HH * WW + (size_t)ir * WW;
        #pragma unroll
        for (int k = 0; k < 8; k++) {
            const float* p = xb + (size_t)(q8 + k) * (HH * WW);
            xcA[k] = p[pjA];
            xcB[k] = p[pjB];
        }
    }
    // gates for both pixels
    const float2* vo2 = (const float2*)(ws + WS_VO2);
    const float2* ho2 = (const float2*)(ws + WS_HO2);
    float2 vA = vo2[pixA], hA = ho2[pixA];
    float2 vB = vo2[pixB], hB = ho2[pixB];
    float gbvA[4], gbvB[4];
    gbvA[0] = 2.f / (1.f + expf(-(vA.x * bnab_s[0] + bnab_s[4])));
    gbvA[1] = 2.f / (1.f + expf(-(vA.y * bnab_s[1] + bnab_s[5])));
    gbvA[2] = 2.f / (1.f + expf(-(hA.x * bnab_s[2] + bnab_s[6])));
    gbvA[3] = 2.f / (1.f + expf(-(hA.y * bnab_s[3] + bnab_s[7])));
    gbvB[0] = 2.f / (1.f + expf(-(vB.x * bnab_s[0] + bnab_s[4])));
    gbvB[1] = 2.f / (1.f + expf(-(vB.y * bnab_s[1] + bnab_s[5])));
    gbvB[2] = 2.f / (1.f + expf(-(hB.x * bnab_s[2] + bnab_s[6])));
    gbvB[3] = 2.f / (1.f + expf(-(hB.y * bnab_s[3] + bnab_s[7])));

    f32x4 accA0 = {0.f,0.f,0.f,0.f}, accA1 = {0.f,0.f,0.f,0.f};
    f32x4 accB0 = {0.f,0.f,0.f,0.f}, accB1 = {0.f,0.f,0.f,0.f};
    float fi = (float)ir + 2.f;
    float fjA = (float)pjA + 2.f, fjB = (float)pjB + 2.f;

    short8 a0 = *(const short8*)(wkb + (size_t)pl * 512 + q8);
    short8 a1 = *(const short8*)(wkb + (size_t)(pl + 16) * 512 + q8);

    float ngA_ = 0.f, ngB_ = 0.f;
    int baseA_ = 0, baseB_ = 0;

    #pragma unroll
    for (int n = 0; n < 16; n++) {
        short8 na0 = a0, na1 = a1;
        if (n < 15) {
            na0 = *(const short8*)(wkb + (size_t)pl * 512 + (n+1)*32 + q8);
            na1 = *(const short8*)(wkb + (size_t)(pl + 16) * 512 + (n+1)*32 + q8);
        }
        if ((n & 3) == 0) {            // group boundary: frac coord constant over 4 n's
            int g = n >> 2;
            float pmA, pmB;
            if (g == 0)      { pmA = (fi  - 2.f) - gbvA[0]; pmB = (fi  - 2.f) - gbvB[0]; }
            else if (g == 1) { pmA = (fjA + 2.f) + gbvA[3]; pmB = (fjB + 2.f) + gbvB[3]; }
            else if (g == 2) { pmA = (fi  + 2.f) + gbvA[1]; pmB = (fi  + 2.f) + gbvB[1]; }
            else             { pmA = (fjA - 2.f) - gbvA[2]; pmB = (fjB - 2.f) - gbvB[2]; }
            int mA, mB;
            frac_setup(pmA, ngA_, mA);
            frac_setup(pmB, ngB_, mB);
            if ((g & 1) == 0) {        // moving axis = row
                baseA_ = (mA - i0 + 4)*1600 + q8;
                baseB_ = (mB - i0 + 4)*1600 + q8;
            } else {                   // moving axis = col
                baseA_ = (mA - j0 + 4)*40 + q8;
                baseB_ = (mB - j0 + 4)*40 + q8;
            }
        }
        short8 bfA, bfB;
        if (n == 11 || n == 15) {      // clip-edge cases: grb can be nonzero
            bfA = sample_frag(tile, xcA, gbvA, fi, fjA, n, prfx[n], prfy[n], i0, j0, quad);
            bfB = sample_frag(tile, xcB, gbvB, fi, fjB, n, prfx[n], prfy[n], i0, j0, quad);
        } else {
            int io = ioffs[n];
            int offA, offB;
            if (((n >> 2) & 1) == 0) { // int axis = col
                int cA = min(max(pjA + io, 0), WW - 1);
                int cB = min(max(pjB + io, 0), WW - 1);
                offA = baseA_ + (cA - j0 + 4)*40;
                offB = baseB_ + (cB - j0 + 4)*40;
            } else {                   // int axis = row (shared by A and B)
                int r  = min(max(ir + io, 0), HH - 1);
                int rt = (r - i0 + 4)*1600;
                offA = baseA_ + rt;
                offB = baseB_ + rt;
            }
            bfA = samp1(tile, xcA, ngA_, offA);
            bfB = samp1(tile, xcB, ngB_, offB);
        }
        accA0 = __builtin_amdgcn_mfma_f32_16x16x32_bf16(a0, bfA, accA0, 0, 0, 0);
        accA1 = __builtin_amdgcn_mfma_f32_16x16x32_bf16(a1, bfA, accA1, 0, 0, 0);
        accB0 = __builtin_amdgcn_mfma_f32_16x16x32_bf16(a0, bfB, accB0, 0, 0, 0);
        accB1 = __builtin_amdgcn_mfma_f32_16x16x32_bf16(a1, bfB, accB1, 0, 0, 0);
        a0 = na0; a1 = na1;
    }
    // epilogue
    float* opA = out + (size_t)b * (OUTC*HH*WW) + ir * WW + pjA;
    float* opB = opA + 16;
    #pragma unroll
    for (int r = 0; r < 4; r++) {
        int o = quad*4 + r;
        float bo = b_pk[o], bo16 = b_pk[o + 16];
        opA[(size_t)o * (HH*WW)]        = accA0[r] + bo;
        opA[(size_t)(o + 16) * (HH*WW)] = accA1[r] + bo16;
        opB[(size_t)o * (HH*WW)]        = accB0[r] + bo;
        opB[(size_t)(o + 16) * (HH*WW)] = accB1[r] + bo16;
    }
}

extern "C" void kernel_launch(void* const* d_in, const int* in_sizes, int n_in,
                              void* d_out, int out_size, void* d_ws, size_t ws_size,
                              hipStream_t stream) {
    const float* x      = (const float*)d_in[0];
    const float* w_vrt  = (const float*)d_in[1];
    const float* b_vrt  = (const float*)d_in[2];
    const float* g_vrt  = (const float*)d_in[3];
    const float* be_vrt = (const float*)d_in[4];
    const float* w_hrz  = (const float*)d_in[5];
    const float* b_hrz  = (const float*)d_in[6];
    const float* g_hrz  = (const float*)d_in[7];
    const float* be_hrz = (const float*)d_in[8];
    const float* w_pk   = (const float*)d_in[9];
    const float* b_pk   = (const float*)d_in[10];
    float* ws  = (float*)d_ws;
    float* out = (float*)d_out;

    k_fused1<<<512 + 1024 + 8, 256, 0, stream>>>(x, w_vrt, b_vrt, w_hrz, b_hrz, w_pk, ws);
    k_main<<<1024, 256, 0, stream>>>(ws, x, g_vrt, be_vrt, g_hrz, be_hrz, b_pk, out);
}